// Round 1
// baseline (3125.239 us; speedup 1.0000x reference)
//
#include <hip/hip_runtime.h>

#define BN_EPS 1e-5f

// ============ generic tiled linear: Y = act(X @ W^T + b), row-major ============
// X: (R, Cin), W: (Cout, Cin), Y: (R, Cout). grid.z = weight-matrix batch.
__global__ __launch_bounds__(256) void linear_kernel(
    const float* __restrict__ X, int Xstride,
    const float* __restrict__ W, int Wstride,
    const float* __restrict__ bias, int bstride,
    float* __restrict__ Y, int Ystride,
    int R, int Cin, int Cout, int relu)
{
    const int mat = blockIdx.z;
    X += mat * Xstride;
    W += mat * Wstride;
    Y += mat * Ystride;
    const float* bp = bias ? bias + mat * bstride : nullptr;

    const int r0 = blockIdx.y * 64;
    const int o0 = blockIdx.x * 64;
    __shared__ float As[16][65];
    __shared__ float Bs[16][65];
    const int tid = threadIdx.x;
    const int tx = tid & 15, ty = tid >> 4;
    float acc[4][4] = {};

    for (int k0 = 0; k0 < Cin; k0 += 16) {
        #pragma unroll
        for (int i = 0; i < 4; i++) {
            int idx = tid + i * 256;
            int rr = idx >> 4, kk = idx & 15;
            int r = r0 + rr;
            As[kk][rr] = (r < R) ? X[r * Cin + k0 + kk] : 0.f;
        }
        #pragma unroll
        for (int i = 0; i < 4; i++) {
            int idx = tid + i * 256;
            int oo = idx >> 4, kk = idx & 15;
            int o = o0 + oo;
            Bs[kk][oo] = (o < Cout) ? W[o * Cin + k0 + kk] : 0.f;
        }
        __syncthreads();
        #pragma unroll
        for (int kk = 0; kk < 16; kk++) {
            float a[4], b[4];
            #pragma unroll
            for (int i = 0; i < 4; i++) a[i] = As[kk][ty * 4 + i];
            #pragma unroll
            for (int j = 0; j < 4; j++) b[j] = Bs[kk][tx * 4 + j];
            #pragma unroll
            for (int i = 0; i < 4; i++)
                #pragma unroll
                for (int j = 0; j < 4; j++)
                    acc[i][j] += a[i] * b[j];
        }
        __syncthreads();
    }
    #pragma unroll
    for (int i = 0; i < 4; i++) {
        int r = r0 + ty * 4 + i;
        if (r >= R) continue;
        #pragma unroll
        for (int j = 0; j < 4; j++) {
            int o = o0 + tx * 4 + j;
            if (o >= Cout) continue;
            float v = acc[i][j];
            if (bp) v += bp[o];
            if (relu) v = fmaxf(v, 0.f);
            Y[r * Cout + o] = v;
        }
    }
}

// ============ BN stats for h: per (k,o) over (b,n)=784. h layout (k,b,n,o) ============
__global__ __launch_bounds__(256) void bn1_stats_kernel(
    const float* __restrict__ h, float* __restrict__ mean, float* __restrict__ rstd)
{
    int k = blockIdx.x;  // 12
    int tid = threadIdx.x;
    #pragma unroll
    for (int half = 0; half < 2; half++) {
        int o = tid + half * 256;
        const float* base = h + k * 401408 + o;
        float s = 0.f, sq = 0.f;
        #pragma unroll 4
        for (int bn = 0; bn < 784; bn++) {
            float v = base[bn * 512];
            s += v; sq += v * v;
        }
        float mu = s * (1.f / 784.f);
        float var = sq * (1.f / 784.f) - mu * mu;
        mean[k * 512 + o] = mu;
        rstd[k * 512 + o] = rsqrtf(var + BN_EPS);
    }
}

// ============ f_u = relu(bn(h)) in place; f_v[b,k,o] = mean_n f_u ============
__global__ __launch_bounds__(256) void fu_fv_kernel(
    float* __restrict__ h, const float* __restrict__ mean,
    const float* __restrict__ rstd, float* __restrict__ f_v)
{
    int b = blockIdx.x;  // 16
    int k = blockIdx.y;  // 12
    int tid = threadIdx.x;
    #pragma unroll
    for (int half = 0; half < 2; half++) {
        int o = tid + half * 256;
        float mu = mean[k * 512 + o], rs = rstd[k * 512 + o];
        float* base = h + (k * 16 + b) * 49 * 512 + o;
        float acc = 0.f;
        #pragma unroll 7
        for (int n = 0; n < 49; n++) {
            float v = (base[n * 512] - mu) * rs;
            v = fmaxf(v, 0.f);
            base[n * 512] = v;
            acc += v;
        }
        f_v[(b * 12 + k) * 512 + o] = acc * (1.f / 49.f);
    }
}

// ============ attn1: feat[k,b] = softmax(q1[k,b] @ k1[b]^T / 16) @ v1[b] ============
__global__ __launch_bounds__(256) void attn1_kernel(
    const float* __restrict__ q1,  // (12,16,49,256)
    const float* __restrict__ k1,  // (16,49,256)
    const float* __restrict__ v1,  // (16,49,512)
    float* __restrict__ feat)      // (12,16,49,512)
{
    int b = blockIdx.x;  // 16
    int k = blockIdx.y;  // 12
    __shared__ float ks[49 * 256];
    __shared__ float P[49][50];
    int tid = threadIdx.x;
    const float* kb = k1 + b * 49 * 256;
    for (int e = tid; e < 49 * 256; e += 256) ks[e] = kb[e];
    __syncthreads();
    const float* qb = q1 + (k * 16 + b) * 49 * 256;
    for (int e = tid; e < 49 * 49; e += 256) {
        int qi = e / 49, kj = e - qi * 49;
        const float4* q4 = reinterpret_cast<const float4*>(qb + qi * 256);
        const float4* k4 = reinterpret_cast<const float4*>(ks + kj * 256);
        float s = 0.f;
        #pragma unroll 8
        for (int d = 0; d < 64; d++) {
            float4 a = q4[d], c = k4[d];
            s += a.x * c.x + a.y * c.y + a.z * c.z + a.w * c.w;
        }
        P[qi][kj] = s * 0.0625f;
    }
    __syncthreads();
    if (tid < 49) {
        float m = -1e30f;
        for (int j = 0; j < 49; j++) m = fmaxf(m, P[tid][j]);
        float s = 0.f;
        for (int j = 0; j < 49; j++) { float e = __expf(P[tid][j] - m); P[tid][j] = e; s += e; }
        float inv = 1.f / s;
        for (int j = 0; j < 49; j++) P[tid][j] *= inv;
    }
    __syncthreads();
    const float* vb = v1 + b * 49 * 512;
    float* fb = feat + (k * 16 + b) * 49 * 512;
    for (int e = tid; e < 49 * 512; e += 256) {
        int qi = e >> 9, c = e & 511;
        float s = 0.f;
        #pragma unroll 7
        for (int j = 0; j < 49; j++) s += P[qi][j] * vb[j * 512 + c];
        fb[e] = s;
    }
}

// ============ attn2 fused: per (b,i,j): P = softmax(q2[j,b] @ k2[i,b]^T / 16)
//   proj = P @ w2v[i,b] + ep_b ; fe_raw[b,i*12+j,:] = mean_n proj ; atomics for slot stats ============
__global__ __launch_bounds__(256) void attn2_kernel(
    const float* __restrict__ q2,   // (12,16,49,256) indexed by j
    const float* __restrict__ k2,   // (12,16,49,256) indexed by i
    const float* __restrict__ w2v,  // (12,16,49,512) indexed by i
    const float* __restrict__ ep_b, // (512)
    float* __restrict__ fe_raw,     // (16,144,512)
    float* __restrict__ stats)      // (144,2)
{
    int b = blockIdx.x;  // 16
    int i = blockIdx.y;  // 12
    int j = blockIdx.z;  // 12
    __shared__ float ks[49 * 256];
    __shared__ float P[49][50];
    __shared__ float red[256];
    int tid = threadIdx.x;
    const float* kb = k2 + (i * 16 + b) * 49 * 256;
    for (int e = tid; e < 49 * 256; e += 256) ks[e] = kb[e];
    __syncthreads();
    const float* qb = q2 + (j * 16 + b) * 49 * 256;
    for (int e = tid; e < 49 * 49; e += 256) {
        int qi = e / 49, kj = e - qi * 49;
        const float4* q4 = reinterpret_cast<const float4*>(qb + qi * 256);
        const float4* k4 = reinterpret_cast<const float4*>(ks + kj * 256);
        float s = 0.f;
        #pragma unroll 8
        for (int d = 0; d < 64; d++) {
            float4 a = q4[d], c = k4[d];
            s += a.x * c.x + a.y * c.y + a.z * c.z + a.w * c.w;
        }
        P[qi][kj] = s * 0.0625f;
    }
    __syncthreads();
    if (tid < 49) {
        float m = -1e30f;
        for (int jj = 0; jj < 49; jj++) m = fmaxf(m, P[tid][jj]);
        float s = 0.f;
        for (int jj = 0; jj < 49; jj++) { float e = __expf(P[tid][jj] - m); P[tid][jj] = e; s += e; }
        float inv = 1.f / s;
        for (int jj = 0; jj < 49; jj++) P[tid][jj] *= inv;
    }
    __syncthreads();
    const float* vb = w2v + (i * 16 + b) * 49 * 512;
    int slot = i * 12 + j;
    float csum[2];
    float csq = 0.f;
    #pragma unroll
    for (int half = 0; half < 2; half++) {
        int c = tid + half * 256;
        float bias = ep_b[c];
        float colsum = 0.f;
        for (int qi = 0; qi < 49; qi++) {
            float s = bias;
            #pragma unroll 7
            for (int kj = 0; kj < 49; kj++) s += P[qi][kj] * vb[kj * 512 + c];
            colsum += s;
            csq += s * s;
        }
        csum[half] = colsum;
        fe_raw[(b * 144 + slot) * 512 + c] = colsum * (1.f / 49.f);
    }
    float tot = csum[0] + csum[1];
    red[tid] = tot; __syncthreads();
    for (int t = 128; t > 0; t >>= 1) { if (tid < t) red[tid] += red[tid + t]; __syncthreads(); }
    if (tid == 0) atomicAdd(&stats[slot * 2], red[0]);
    __syncthreads();
    red[tid] = csq; __syncthreads();
    for (int t = 128; t > 0; t >>= 1) { if (tid < t) red[tid] += red[tid + t]; __syncthreads(); }
    if (tid == 0) atomicAdd(&stats[slot * 2 + 1], red[0]);
}

// ============ finalize edge BN: f_e = (fe_raw - mu_s) * rstd_s ============
__global__ __launch_bounds__(256) void edge_fin_kernel(
    const float* __restrict__ stats, float* __restrict__ fe)
{
    int s = blockIdx.x;  // 144
    const float inv = 1.f / 401408.f;
    float mu = stats[s * 2] * inv;
    float var = stats[s * 2 + 1] * inv - mu * mu;
    float rs = rsqrtf(var + BN_EPS);
    int tid = threadIdx.x;
    for (int b = 0; b < 16; b++) {
        float* p = fe + (b * 144 + s) * 512;
        #pragma unroll
        for (int half = 0; half < 2; half++) {
            int c = tid + half * 256;
            p[c] = (p[c] - mu) * rs;
        }
    }
}

// ============ GNN edge update: msg = Vjx[i]+Vix[j]+eE ; fe += relu(bn_slot(msg)) ============
__global__ __launch_bounds__(256) void gnn_edge_kernel(
    const float* __restrict__ nodeproj,  // [4][16][12][512] : 0=Ux 1=Ujx 2=Vix 3=Vjx
    const float* __restrict__ eE,        // (16,144,512)
    float* __restrict__ fe)              // (16,144,512) in/out
{
    int s = blockIdx.x;  // 144
    int i = s / 12, j = s - i * 12;
    int tid = threadIdx.x;
    const float* Vix = nodeproj + 2 * 98304;
    const float* Vjx = nodeproj + 3 * 98304;
    __shared__ float red[256];
    float msg[32];
    float sum = 0.f, sq = 0.f;
    int idx = 0;
    for (int b = 0; b < 16; b++) {
        #pragma unroll
        for (int half = 0; half < 2; half++) {
            int c = tid + half * 256;
            float v = Vjx[(b * 12 + i) * 512 + c] + Vix[(b * 12 + j) * 512 + c]
                    + eE[(b * 144 + s) * 512 + c];
            msg[idx++] = v;
            sum += v; sq += v * v;
        }
    }
    red[tid] = sum; __syncthreads();
    for (int t = 128; t > 0; t >>= 1) { if (tid < t) red[tid] += red[tid + t]; __syncthreads(); }
    float tsum = red[0]; __syncthreads();
    red[tid] = sq; __syncthreads();
    for (int t = 128; t > 0; t >>= 1) { if (tid < t) red[tid] += red[tid + t]; __syncthreads(); }
    float tsq = red[0];
    float mu = tsum * (1.f / 8192.f);
    float var = tsq * (1.f / 8192.f) - mu * mu;
    float rs = rsqrtf(var + BN_EPS);
    idx = 0;
    for (int b = 0; b < 16; b++) {
        #pragma unroll
        for (int half = 0; half < 2; half++) {
            int c = tid + half * 256;
            float v = fmaxf((msg[idx++] - mu) * rs, 0.f);
            fe[(b * 144 + s) * 512 + c] += v;
        }
    }
}

// ============ GNN softmax-over-j aggregation: xn = Ux + (1/12) Σ_i softmax_j(sig(edge)) * Ujx[i] ============
__global__ __launch_bounds__(256) void gnn_agg_kernel(
    const float* __restrict__ fe,        // updated edges (16,144,512)
    const float* __restrict__ nodeproj,  // 0=Ux 1=Ujx
    float* __restrict__ xn)              // (16,12,512)
{
    int b = blockIdx.x;  // 16
    int tid = threadIdx.x;
    const float* Ux = nodeproj;
    const float* Ujx = nodeproj + 98304;
    #pragma unroll
    for (int half = 0; half < 2; half++) {
        int c = tid + half * 256;
        float agg[12];
        #pragma unroll
        for (int j = 0; j < 12; j++) agg[j] = 0.f;
        for (int i = 0; i < 12; i++) {
            float sg[12];
            float m = -1e30f;
            #pragma unroll
            for (int j = 0; j < 12; j++) {
                float e = fe[(b * 144 + i * 12 + j) * 512 + c];
                float sv = 1.f / (1.f + __expf(-e));
                sg[j] = sv;
                m = fmaxf(m, sv);
            }
            float ssum = 0.f;
            #pragma unroll
            for (int j = 0; j < 12; j++) { float ev = __expf(sg[j] - m); sg[j] = ev; ssum += ev; }
            float w = Ujx[(b * 12 + i) * 512 + c] / ssum;
            #pragma unroll
            for (int j = 0; j < 12; j++) agg[j] += sg[j] * w;
        }
        #pragma unroll
        for (int j = 0; j < 12; j++)
            xn[(b * 12 + j) * 512 + c] = Ux[(b * 12 + j) * 512 + c] + agg[j] * (1.f / 12.f);
    }
}

// ============ GNN node update: fv = relu(fv + bn_class(xn)) ============
__global__ __launch_bounds__(256) void gnn_node_kernel(
    const float* __restrict__ xn, float* __restrict__ fv)
{
    int k = blockIdx.x;  // 12
    int tid = threadIdx.x;
    __shared__ float red[256];
    float vals[32];
    float sum = 0.f, sq = 0.f;
    int idx = 0;
    for (int b = 0; b < 16; b++) {
        #pragma unroll
        for (int half = 0; half < 2; half++) {
            int c = tid + half * 256;
            float v = xn[(b * 12 + k) * 512 + c];
            vals[idx++] = v;
            sum += v; sq += v * v;
        }
    }
    red[tid] = sum; __syncthreads();
    for (int t = 128; t > 0; t >>= 1) { if (tid < t) red[tid] += red[tid + t]; __syncthreads(); }
    float tsum = red[0]; __syncthreads();
    red[tid] = sq; __syncthreads();
    for (int t = 128; t > 0; t >>= 1) { if (tid < t) red[tid] += red[tid + t]; __syncthreads(); }
    float tsq = red[0];
    float mu = tsum * (1.f / 8192.f);
    float var = tsq * (1.f / 8192.f) - mu * mu;
    float rs = rsqrtf(var + BN_EPS);
    idx = 0;
    for (int b = 0; b < 16; b++) {
        #pragma unroll
        for (int half = 0; half < 2; half++) {
            int c = tid + half * 256;
            int o = (b * 12 + k) * 512 + c;
            float v = (vals[idx++] - mu) * rs;
            fv[o] = fmaxf(fv[o] + v, 0.f);
        }
    }
}

// ============ gather pairwise features: pairX[0]=edges (B,66,1024), pairX[1]=nodes ============
__global__ __launch_bounds__(256) void pair_gather_kernel(
    const float* __restrict__ fe, const float* __restrict__ fv, float* __restrict__ pairX)
{
    int p = blockIdx.x;  // 66
    int b = blockIdx.y;  // 16
    int tid = threadIdx.x;
    int i = 0, rem = p;
    while (rem >= 11 - i) { rem -= 11 - i; i++; }
    int j = i + 1 + rem;
    float* e_out = pairX + (b * 66 + p) * 1024;
    float* n_out = pairX + 1056 * 1024 + (b * 66 + p) * 1024;
    const float* fe_ij = fe + (b * 144 + i * 12 + j) * 512;
    const float* fe_ji = fe + (b * 144 + j * 12 + i) * 512;
    const float* fv_i = fv + (b * 12 + i) * 512;
    const float* fv_j = fv + (b * 12 + j) * 512;
    #pragma unroll
    for (int half = 0; half < 2; half++) {
        int c = tid + half * 256;
        e_out[c] = fe_ij[c];
        e_out[512 + c] = fe_ji[c];
        n_out[c] = fv_i[c];
        n_out[512 + c] = fv_j[c];
    }
}

// ============ MLP layer 3 (Cout=4) ============
__global__ __launch_bounds__(256) void mlp3_kernel(
    const float* __restrict__ X,   // [2][1056][256]
    const float* __restrict__ w3,  // [2][4][256]
    const float* __restrict__ b3,  // [2][4]
    float* __restrict__ Y)         // [2][1056][4]
{
    int idx = blockIdx.x * 256 + threadIdx.x;  // 8448
    if (idx >= 8448) return;
    int o = idx & 3;
    int r = (idx >> 2) % 1056;
    int m = idx / (4 * 1056);
    const float* x = X + (m * 1056 + r) * 256;
    const float* w = w3 + (m * 4 + o) * 256;
    float s = b3[m * 4 + o];
    #pragma unroll 8
    for (int c = 0; c < 256; c++) s += x[c] * w[c];
    Y[idx] = s;
}

// ============ final: out = concat(ed,nd) @ final_w^T + final_b ============
__global__ __launch_bounds__(256) void final_kernel(
    const float* __restrict__ mid3,  // [2][1056][4]
    const float* __restrict__ fw,    // (4,8)
    const float* __restrict__ fb,    // (4)
    float* __restrict__ out)         // (1056,4)
{
    int idx = blockIdx.x * 256 + threadIdx.x;  // 4224
    if (idx >= 4224) return;
    int o = idx & 3;
    int r = idx >> 2;
    const float* ed = mid3 + r * 4;
    const float* nd = mid3 + 1056 * 4 + r * 4;
    float s = fb[o];
    #pragma unroll
    for (int q = 0; q < 4; q++) s += ed[q] * fw[o * 8 + q];
    #pragma unroll
    for (int q = 0; q < 4; q++) s += nd[q] * fw[o * 8 + 4 + q];
    out[idx] = s;
}

extern "C" void kernel_launch(void* const* d_in, const int* in_sizes, int n_in,
                              void* d_out, int out_size, void* d_ws, size_t ws_size,
                              hipStream_t stream)
{
    const float* x      = (const float*)d_in[0];
    const float* cls_w  = (const float*)d_in[1];
    const float* cls_b  = (const float*)d_in[2];
    const float* qw     = (const float*)d_in[3];
    const float* qb     = (const float*)d_in[4];
    const float* kw     = (const float*)d_in[5];
    const float* kb     = (const float*)d_in[6];
    const float* vw     = (const float*)d_in[7];
    const float* vb     = (const float*)d_in[8];
    const float* ep_w   = (const float*)d_in[9];
    const float* ep_b   = (const float*)d_in[10];
    const float* gnn_w  = (const float*)d_in[11];
    const float* mlp_w1 = (const float*)d_in[12];
    const float* mlp_b1 = (const float*)d_in[13];
    const float* mlp_w2 = (const float*)d_in[14];
    const float* mlp_b2 = (const float*)d_in[15];
    const float* mlp_w3 = (const float*)d_in[16];
    const float* mlp_b3 = (const float*)d_in[17];
    const float* fin_w  = (const float*)d_in[18];
    const float* fin_b  = (const float*)d_in[19];
    float* out = (float*)d_out;
    float* ws = (float*)d_ws;

    // ---- workspace layout (floats), ~71.5 MiB total ----
    float* A     = ws;               // 4816896 : h/f_u (k,b,n,512) -> later q2(0..) + k2(+2408448)
    float* q1b   = A + 4816896;      // 2408448 : q1 (k,b,n,256)
    float* k1b   = q1b + 2408448;    // 200704  : k1 (b,n,256)
    float* v1b   = k1b + 200704;     // 401408  : v1 (b,n,512)
    float* Bb    = v1b + 401408;     // 4816896 : feat (k,b,n,512) -> later w2v
    float* Cb    = Bb + 4816896;     // 4816896 : v2 -> gnn temps -> pair temps
    float* fv    = Cb + 4816896;     // 98304   : f_v (b,k,512)
    float* bn1m  = fv + 98304;       // 6144
    float* bn1r  = bn1m + 6144;      // 6144
    float* fe    = bn1r + 6144;      // 1179648 : fe_raw then f_e (b,s,512)
    float* stats = fe + 1179648;     // 288

    float* q2b = A;
    float* k2b = A + 2408448;
    float* v2b = Cb;
    float* w2v = Bb;

    // GNN temps in Cb
    float* nodeproj = Cb;            // [4][16][12][512] = 393216
    float* eE       = Cb + 393216;   // 1179648
    float* xn       = Cb + 1572864;  // 98304
    // pair temps in Cb (GNN temps dead)
    float* pairX = Cb;               // 2162688
    float* mid1  = Cb + 2162688;     // 1081344
    float* mid2  = Cb + 3244032;     // 540672
    float* mid3  = Cb + 3784704;     // 8448

    // 1. h[k,b,n,o] = x @ cls_w[k]^T + cls_b[k]
    linear_kernel<<<dim3(8, 13, 12), 256, 0, stream>>>(x, 0, cls_w, 262144, cls_b, 512,
                                                       A, 401408, 784, 512, 512, 0);
    // 2-3. BN over (b,n) per (k,o); f_u=relu(bn(h)) in place; f_v = mean_n
    bn1_stats_kernel<<<12, 256, 0, stream>>>(A, bn1m, bn1r);
    fu_fv_kernel<<<dim3(16, 12), 256, 0, stream>>>(A, bn1m, bn1r, fv);
    // 4. q1 = f_u @ qw0^T + qb0
    linear_kernel<<<dim3(4, 147, 1), 256, 0, stream>>>(A, 0, qw, 0, qb, 0,
                                                       q1b, 0, 9408, 512, 256, 0);
    // 5-6. k1/v1 from x (shared across classes)
    linear_kernel<<<dim3(4, 13, 1), 256, 0, stream>>>(x, 0, kw, 0, kb, 0,
                                                      k1b, 0, 784, 512, 256, 0);
    linear_kernel<<<dim3(8, 13, 1), 256, 0, stream>>>(x, 0, vw, 0, vb, 0,
                                                      v1b, 0, 784, 512, 512, 0);
    // 7. feat = attn1
    attn1_kernel<<<dim3(16, 12), 256, 0, stream>>>(q1b, k1b, v1b, Bb);
    // 8-10. q2/k2/v2 from feat (weights set [1])
    linear_kernel<<<dim3(4, 147, 1), 256, 0, stream>>>(Bb, 0, qw + 131072, 0, qb + 256, 0,
                                                       q2b, 0, 9408, 512, 256, 0);
    linear_kernel<<<dim3(4, 147, 1), 256, 0, stream>>>(Bb, 0, kw + 131072, 0, kb + 256, 0,
                                                       k2b, 0, 9408, 512, 256, 0);
    linear_kernel<<<dim3(8, 147, 1), 256, 0, stream>>>(Bb, 0, vw + 262144, 0, vb + 512, 0,
                                                       v2b, 0, 9408, 512, 512, 0);
    // 11. w2v = v2 @ ep_w^T  (ep hoisted through attention)
    linear_kernel<<<dim3(8, 147, 1), 256, 0, stream>>>(v2b, 0, ep_w, 0, nullptr, 0,
                                                       w2v, 0, 9408, 512, 512, 0);
    // 12-14. fused attn2 + edge BN stats + finalize -> f_e
    hipMemsetAsync(stats, 0, 288 * sizeof(float), stream);
    attn2_kernel<<<dim3(16, 12, 12), 256, 0, stream>>>(q2b, k2b, w2v, ep_b, fe, stats);
    edge_fin_kernel<<<144, 256, 0, stream>>>(stats, fe);

    // 15-16. two GCN blocks
    for (int blk = 0; blk < 2; blk++) {
        const float* gw = gnn_w + blk * 5 * 262144;  // U,V,A,B,E
        linear_kernel<<<dim3(8, 3, 4), 256, 0, stream>>>(fv, 0, gw, 262144, nullptr, 0,
                                                         nodeproj, 98304, 192, 512, 512, 0);
        linear_kernel<<<dim3(8, 36, 1), 256, 0, stream>>>(fe, 0, gw + 4 * 262144, 0, nullptr, 0,
                                                          eE, 0, 2304, 512, 512, 0);
        gnn_edge_kernel<<<144, 256, 0, stream>>>(nodeproj, eE, fe);
        gnn_agg_kernel<<<16, 256, 0, stream>>>(fe, nodeproj, xn);
        gnn_node_kernel<<<12, 256, 0, stream>>>(xn, fv);
    }

    // 17. pairwise gather
    pair_gather_kernel<<<dim3(66, 16), 256, 0, stream>>>(fe, fv, pairX);
    // 18-19. MLP layers 1-2 (edge head m=0, node head m=1)
    linear_kernel<<<dim3(8, 17, 2), 256, 0, stream>>>(pairX, 1081344, mlp_w1, 524288, mlp_b1, 512,
                                                      mid1, 540672, 1056, 1024, 512, 1);
    linear_kernel<<<dim3(4, 17, 2), 256, 0, stream>>>(mid1, 540672, mlp_w2, 131072, mlp_b2, 256,
                                                      mid2, 270336, 1056, 512, 256, 1);
    // 20. MLP layer 3
    mlp3_kernel<<<33, 256, 0, stream>>>(mid2, mlp_w3, mlp_b3, mid3);
    // 21. final head
    final_kernel<<<17, 256, 0, stream>>>(mid3, fin_w, fin_b, out);
}

// Round 4
// 1036.122 us; speedup vs baseline: 3.0163x; 3.0163x over previous
//
#include <hip/hip_runtime.h>

#define BN_EPS 1e-5f

typedef float f32x4 __attribute__((ext_vector_type(4)));
typedef short s16x8 __attribute__((ext_vector_type(8)));

__device__ __forceinline__ short f2bf(float f) {
    unsigned u = __builtin_bit_cast(unsigned, f);
    u = (u + 0x7fffu + ((u >> 16) & 1u)) >> 16;   // RNE
    return (short)u;
}

// ============ MFMA bf16 linear: Y = act(X @ W^T + b), fp32 in/out ============
// X: (R, Cin) fp32, W: (Cout, Cin) fp32, Y: (R, Cout) fp32. grid.z = matrix batch.
// tile 64x64, BK=32, 4 waves each computing a 32x32 quadrant (2x2 of 16x16x32 MFMA).
// Requires: Cin % 32 == 0, Cout % 64 == 0.
__global__ __launch_bounds__(256) void mfma_linear_kernel(
    const float* __restrict__ X, int Xstride,
    const float* __restrict__ W, int Wstride,
    const float* __restrict__ bias, int bstride,
    float* __restrict__ Y, int Ystride,
    int R, int Cin, int Cout, int relu)
{
    const int mat = blockIdx.z;
    X += (size_t)mat * Xstride;
    W += (size_t)mat * Wstride;
    Y += (size_t)mat * Ystride;
    const float* bp = bias ? bias + mat * bstride : nullptr;

    const int r0 = blockIdx.y * 64;
    const int o0 = blockIdx.x * 64;

    __shared__ short As[64 * 40];   // row stride 40 shorts (80B = 20 banks: 2-way alias, free)
    __shared__ short Bs[64 * 40];

    const int tid = threadIdx.x;
    const int lane = tid & 63;
    const int wave = tid >> 6;
    const int wr = wave >> 1, wc = wave & 1;     // 2x2 wave grid of 32x32 quadrants
    const int l15 = lane & 15;
    const int lk = lane >> 4;                     // k-group 0..3

    const int trow = tid >> 2;                    // 0..63
    const int tseg = (tid & 3) * 8;               // 0,8,16,24

    f32x4 acc[2][2] = {};

    const int arow = r0 + trow;
    const bool aok = arow < R;
    const float* xrow = X + (size_t)arow * Cin + tseg;
    const float* wrow = W + (size_t)(o0 + trow) * Cin + tseg;

    for (int k0 = 0; k0 < Cin; k0 += 32) {
        // stage A (64 rows x 32 k) as bf16
        float4 a0 = {}, a1 = {};
        if (aok) {
            a0 = *reinterpret_cast<const float4*>(xrow + k0);
            a1 = *reinterpret_cast<const float4*>(xrow + k0 + 4);
        }
        float4 b0 = *reinterpret_cast<const float4*>(wrow + k0);
        float4 b1 = *reinterpret_cast<const float4*>(wrow + k0 + 4);
        s16x8 av, bv;
        av[0] = f2bf(a0.x); av[1] = f2bf(a0.y); av[2] = f2bf(a0.z); av[3] = f2bf(a0.w);
        av[4] = f2bf(a1.x); av[5] = f2bf(a1.y); av[6] = f2bf(a1.z); av[7] = f2bf(a1.w);
        bv[0] = f2bf(b0.x); bv[1] = f2bf(b0.y); bv[2] = f2bf(b0.z); bv[3] = f2bf(b0.w);
        bv[4] = f2bf(b1.x); bv[5] = f2bf(b1.y); bv[6] = f2bf(b1.z); bv[7] = f2bf(b1.w);
        *reinterpret_cast<s16x8*>(&As[trow * 40 + tseg]) = av;
        *reinterpret_cast<s16x8*>(&Bs[trow * 40 + tseg]) = bv;
        __syncthreads();

        s16x8 af[2], bf[2];
        #pragma unroll
        for (int mi = 0; mi < 2; mi++)
            af[mi] = *reinterpret_cast<const s16x8*>(&As[(wr * 32 + mi * 16 + l15) * 40 + lk * 8]);
        #pragma unroll
        for (int ni = 0; ni < 2; ni++)
            bf[ni] = *reinterpret_cast<const s16x8*>(&Bs[(wc * 32 + ni * 16 + l15) * 40 + lk * 8]);
        #pragma unroll
        for (int mi = 0; mi < 2; mi++)
            #pragma unroll
            for (int ni = 0; ni < 2; ni++)
                acc[mi][ni] = __builtin_amdgcn_mfma_f32_16x16x32_bf16(af[mi], bf[ni], acc[mi][ni], 0, 0, 0);
        __syncthreads();
    }

    // epilogue: D col = lane&15, row = (lane>>4)*4 + reg
    #pragma unroll
    for (int mi = 0; mi < 2; mi++) {
        #pragma unroll
        for (int ni = 0; ni < 2; ni++) {
            int col = o0 + wc * 32 + ni * 16 + l15;
            int row0 = r0 + wr * 32 + mi * 16 + lk * 4;
            float bb = bp ? bp[col] : 0.f;
            #pragma unroll
            for (int r = 0; r < 4; r++) {
                int row = row0 + r;
                if (row < R) {
                    float v = acc[mi][ni][r] + bb;
                    if (relu) v = fmaxf(v, 0.f);
                    Y[(size_t)row * Cout + col] = v;
                }
            }
        }
    }
}

// ============ BN stats for h: per (k,o) over (b,n)=784. h layout (k,b,n,o) ============
__global__ __launch_bounds__(256) void bn1_stats_kernel(
    const float* __restrict__ h, float* __restrict__ mean, float* __restrict__ rstd)
{
    int k = blockIdx.x;  // 12
    int tid = threadIdx.x;
    #pragma unroll
    for (int half = 0; half < 2; half++) {
        int o = tid + half * 256;
        const float* base = h + k * 401408 + o;
        float s = 0.f, sq = 0.f;
        #pragma unroll 4
        for (int bn = 0; bn < 784; bn++) {
            float v = base[bn * 512];
            s += v; sq += v * v;
        }
        float mu = s * (1.f / 784.f);
        float var = sq * (1.f / 784.f) - mu * mu;
        mean[k * 512 + o] = mu;
        rstd[k * 512 + o] = rsqrtf(var + BN_EPS);
    }
}

// ============ f_u = relu(bn(h)) in place; f_v[b,k,o] = mean_n f_u ============
__global__ __launch_bounds__(256) void fu_fv_kernel(
    float* __restrict__ h, const float* __restrict__ mean,
    const float* __restrict__ rstd, float* __restrict__ f_v)
{
    int b = blockIdx.x;  // 16
    int k = blockIdx.y;  // 12
    int tid = threadIdx.x;
    #pragma unroll
    for (int half = 0; half < 2; half++) {
        int o = tid + half * 256;
        float mu = mean[k * 512 + o], rs = rstd[k * 512 + o];
        float* base = h + (k * 16 + b) * 49 * 512 + o;
        float acc = 0.f;
        #pragma unroll 7
        for (int n = 0; n < 49; n++) {
            float v = (base[n * 512] - mu) * rs;
            v = fmaxf(v, 0.f);
            base[n * 512] = v;
            acc += v;
        }
        f_v[(b * 12 + k) * 512 + o] = acc * (1.f / 49.f);
    }
}

// ============ attn1: feat[k,b] = softmax(q1[k,b] @ k1[b]^T / 16) @ v1[b] ============
__global__ __launch_bounds__(256) void attn1_kernel(
    const float* __restrict__ q1,  // (12,16,49,256)
    const float* __restrict__ k1,  // (16,49,256)
    const float* __restrict__ v1,  // (16,49,512)
    float* __restrict__ feat)      // (12,16,49,512)
{
    int b = blockIdx.x;  // 16
    int k = blockIdx.y;  // 12
    __shared__ float ks[49 * 260];   // padded stride: conflict-free
    __shared__ float Pt[49 * 56];    // transposed scores: Pt[kj*56 + qi]
    int tid = threadIdx.x;
    const float* kb = k1 + b * 49 * 256;
    for (int e = tid; e < 49 * 256; e += 256) ks[(e >> 8) * 260 + (e & 255)] = kb[e];
    __syncthreads();
    const float* qb = q1 + (k * 16 + b) * 49 * 256;
    for (int e = tid; e < 49 * 49; e += 256) {
        int qi = e / 49, kj = e - qi * 49;
        const float4* q4 = reinterpret_cast<const float4*>(qb + qi * 256);
        const float4* k4 = reinterpret_cast<const float4*>(ks + kj * 260);
        float s = 0.f;
        #pragma unroll 8
        for (int d = 0; d < 64; d++) {
            float4 a = q4[d], c = k4[d];
            s += a.x * c.x + a.y * c.y + a.z * c.z + a.w * c.w;
        }
        Pt[kj * 56 + qi] = s * 0.0625f;
    }
    __syncthreads();
    // wave-parallel softmax over columns of Pt: 4 lanes per row qi
    if (tid < 196) {
        int qi = tid >> 2, sub = tid & 3;
        float ev[13];
        float m = -1e30f;
        #pragma unroll 13
        for (int t = 0; t < 13; t++) {
            int j = sub + t * 4;
            ev[t] = (j < 49) ? Pt[j * 56 + qi] : -1e30f;
            m = fmaxf(m, ev[t]);
        }
        m = fmaxf(m, __shfl_xor(m, 1));
        m = fmaxf(m, __shfl_xor(m, 2));
        float s = 0.f;
        #pragma unroll 13
        for (int t = 0; t < 13; t++) { ev[t] = __expf(ev[t] - m); s += ev[t]; }
        s += __shfl_xor(s, 1);
        s += __shfl_xor(s, 2);
        float inv = 1.f / s;
        #pragma unroll 13
        for (int t = 0; t < 13; t++) {
            int j = sub + t * 4;
            if (j < 49) Pt[j * 56 + qi] = ev[t] * inv;
        }
    }
    __syncthreads();
    // PV: register-chunked over qi, broadcast P columns
    const float* vb = v1 + b * 49 * 512;
    float* fb = feat + (k * 16 + b) * 49 * 512;
    for (int qc = 0; qc < 49; qc += 8) {
        int nq = 49 - qc; if (nq > 8) nq = 8;
        float a0[8] = {}, a1[8] = {};
        for (int kj = 0; kj < 49; kj++) {
            float v0 = vb[kj * 512 + tid];
            float v1v = vb[kj * 512 + 256 + tid];
            const float4* pr = reinterpret_cast<const float4*>(&Pt[kj * 56 + qc]);
            float4 p0 = pr[0], p1 = pr[1];
            a0[0] += p0.x * v0; a1[0] += p0.x * v1v;
            a0[1] += p0.y * v0; a1[1] += p0.y * v1v;
            a0[2] += p0.z * v0; a1[2] += p0.z * v1v;
            a0[3] += p0.w * v0; a1[3] += p0.w * v1v;
            a0[4] += p1.x * v0; a1[4] += p1.x * v1v;
            a0[5] += p1.y * v0; a1[5] += p1.y * v1v;
            a0[6] += p1.z * v0; a1[6] += p1.z * v1v;
            a0[7] += p1.w * v0; a1[7] += p1.w * v1v;
        }
        #pragma unroll 8
        for (int u = 0; u < 8; u++) {
            if (u < nq) {
                fb[(qc + u) * 512 + tid] = a0[u];
                fb[(qc + u) * 512 + 256 + tid] = a1[u];
            }
        }
    }
}

// ============ attn2 fused: per (b,i,j): P = softmax(q2[j,b] @ k2[i,b]^T / 16)
//   proj = P @ w2v[i,b] + ep_b ; fe_raw[b,i*12+j,:] = mean_n proj ; atomics for slot stats ============
__global__ __launch_bounds__(256) void attn2_kernel(
    const float* __restrict__ q2,   // (12,16,49,256) indexed by j
    const float* __restrict__ k2,   // (12,16,49,256) indexed by i
    const float* __restrict__ w2v,  // (12,16,49,512) indexed by i
    const float* __restrict__ ep_b, // (512)
    float* __restrict__ fe_raw,     // (16,144,512)
    float* __restrict__ stats)      // (144,2)
{
    int b = blockIdx.x;  // 16
    int i = blockIdx.y;  // 12
    int j = blockIdx.z;  // 12
    __shared__ float ks[49 * 260];
    __shared__ float Pt[49 * 56];
    __shared__ float red[256];
    int tid = threadIdx.x;
    const float* kb = k2 + (i * 16 + b) * 49 * 256;
    for (int e = tid; e < 49 * 256; e += 256) ks[(e >> 8) * 260 + (e & 255)] = kb[e];
    __syncthreads();
    const float* qb = q2 + (j * 16 + b) * 49 * 256;
    for (int e = tid; e < 49 * 49; e += 256) {
        int qi = e / 49, kj = e - qi * 49;
        const float4* q4 = reinterpret_cast<const float4*>(qb + qi * 256);
        const float4* k4 = reinterpret_cast<const float4*>(ks + kj * 260);
        float s = 0.f;
        #pragma unroll 8
        for (int d = 0; d < 64; d++) {
            float4 a = q4[d], c = k4[d];
            s += a.x * c.x + a.y * c.y + a.z * c.z + a.w * c.w;
        }
        Pt[kj * 56 + qi] = s * 0.0625f;
    }
    __syncthreads();
    if (tid < 196) {
        int qi = tid >> 2, sub = tid & 3;
        float ev[13];
        float m = -1e30f;
        #pragma unroll 13
        for (int t = 0; t < 13; t++) {
            int jj = sub + t * 4;
            ev[t] = (jj < 49) ? Pt[jj * 56 + qi] : -1e30f;
            m = fmaxf(m, ev[t]);
        }
        m = fmaxf(m, __shfl_xor(m, 1));
        m = fmaxf(m, __shfl_xor(m, 2));
        float s = 0.f;
        #pragma unroll 13
        for (int t = 0; t < 13; t++) { ev[t] = __expf(ev[t] - m); s += ev[t]; }
        s += __shfl_xor(s, 1);
        s += __shfl_xor(s, 2);
        float inv = 1.f / s;
        #pragma unroll 13
        for (int t = 0; t < 13; t++) {
            int jj = sub + t * 4;
            if (jj < 49) Pt[jj * 56 + qi] = ev[t] * inv;
        }
    }
    __syncthreads();
    const float* vb = w2v + (i * 16 + b) * 49 * 512;
    int slot = i * 12 + j;
    float bias0 = ep_b[tid], bias1 = ep_b[tid + 256];
    float colsum0 = 0.f, colsum1 = 0.f, csq = 0.f;
    for (int qc = 0; qc < 49; qc += 8) {
        int nq = 49 - qc; if (nq > 8) nq = 8;
        float a0[8] = {}, a1[8] = {};
        for (int kj = 0; kj < 49; kj++) {
            float v0 = vb[kj * 512 + tid];
            float v1v = vb[kj * 512 + 256 + tid];
            const float4* pr = reinterpret_cast<const float4*>(&Pt[kj * 56 + qc]);
            float4 p0 = pr[0], p1 = pr[1];
            a0[0] += p0.x * v0; a1[0] += p0.x * v1v;
            a0[1] += p0.y * v0; a1[1] += p0.y * v1v;
            a0[2] += p0.z * v0; a1[2] += p0.z * v1v;
            a0[3] += p0.w * v0; a1[3] += p0.w * v1v;
            a0[4] += p1.x * v0; a1[4] += p1.x * v1v;
            a0[5] += p1.y * v0; a1[5] += p1.y * v1v;
            a0[6] += p1.z * v0; a1[6] += p1.z * v1v;
            a0[7] += p1.w * v0; a1[7] += p1.w * v1v;
        }
        #pragma unroll 8
        for (int u = 0; u < 8; u++) {
            if (u < nq) {
                float s0 = a0[u] + bias0, s1 = a1[u] + bias1;
                colsum0 += s0; colsum1 += s1;
                csq += s0 * s0 + s1 * s1;
            }
        }
    }
    fe_raw[(b * 144 + slot) * 512 + tid] = colsum0 * (1.f / 49.f);
    fe_raw[(b * 144 + slot) * 512 + 256 + tid] = colsum1 * (1.f / 49.f);
    float tot = colsum0 + colsum1;
    red[tid] = tot; __syncthreads();
    for (int t = 128; t > 0; t >>= 1) { if (tid < t) red[tid] += red[tid + t]; __syncthreads(); }
    if (tid == 0) atomicAdd(&stats[slot * 2], red[0]);
    __syncthreads();
    red[tid] = csq; __syncthreads();
    for (int t = 128; t > 0; t >>= 1) { if (tid < t) red[tid] += red[tid + t]; __syncthreads(); }
    if (tid == 0) atomicAdd(&stats[slot * 2 + 1], red[0]);
}

// ============ finalize edge BN: f_e = (fe_raw - mu_s) * rstd_s ============
__global__ __launch_bounds__(256) void edge_fin_kernel(
    const float* __restrict__ stats, float* __restrict__ fe)
{
    int s = blockIdx.x;  // 144
    const float inv = 1.f / 401408.f;
    float mu = stats[s * 2] * inv;
    float var = stats[s * 2 + 1] * inv - mu * mu;
    float rs = rsqrtf(var + BN_EPS);
    int tid = threadIdx.x;
    for (int b = 0; b < 16; b++) {
        float* p = fe + (b * 144 + s) * 512;
        #pragma unroll
        for (int half = 0; half < 2; half++) {
            int c = tid + half * 256;
            p[c] = (p[c] - mu) * rs;
        }
    }
}

// ============ GNN edge update: msg = Vjx[i]+Vix[j]+eE ; fe += relu(bn_slot(msg)) ============
__global__ __launch_bounds__(256) void gnn_edge_kernel(
    const float* __restrict__ nodeproj,  // [4][16][12][512] : 0=Ux 1=Ujx 2=Vix 3=Vjx
    const float* __restrict__ eE,        // (16,144,512)
    float* __restrict__ fe)              // (16,144,512) in/out
{
    int s = blockIdx.x;  // 144
    int i = s / 12, j = s - i * 12;
    int tid = threadIdx.x;
    const float* Vix = nodeproj + 2 * 98304;
    const float* Vjx = nodeproj + 3 * 98304;
    __shared__ float red[256];
    float msg[32];
    float sum = 0.f, sq = 0.f;
    int idx = 0;
    for (int b = 0; b < 16; b++) {
        #pragma unroll
        for (int half = 0; half < 2; half++) {
            int c = tid + half * 256;
            float v = Vjx[(b * 12 + i) * 512 + c] + Vix[(b * 12 + j) * 512 + c]
                    + eE[(b * 144 + s) * 512 + c];
            msg[idx++] = v;
            sum += v; sq += v * v;
        }
    }
    red[tid] = sum; __syncthreads();
    for (int t = 128; t > 0; t >>= 1) { if (tid < t) red[tid] += red[tid + t]; __syncthreads(); }
    float tsum = red[0]; __syncthreads();
    red[tid] = sq; __syncthreads();
    for (int t = 128; t > 0; t >>= 1) { if (tid < t) red[tid] += red[tid + t]; __syncthreads(); }
    float tsq = red[0];
    float mu = tsum * (1.f / 8192.f);
    float var = tsq * (1.f / 8192.f) - mu * mu;
    float rs = rsqrtf(var + BN_EPS);
    idx = 0;
    for (int b = 0; b < 16; b++) {
        #pragma unroll
        for (int half = 0; half < 2; half++) {
            int c = tid + half * 256;
            float v = fmaxf((msg[idx++] - mu) * rs, 0.f);
            fe[(b * 144 + s) * 512 + c] += v;
        }
    }
}

// ============ GNN softmax-over-j aggregation: xn = Ux + (1/12) Σ_i softmax_j(sig(edge)) * Ujx[i] ============
__global__ __launch_bounds__(256) void gnn_agg_kernel(
    const float* __restrict__ fe,        // updated edges (16,144,512)
    const float* __restrict__ nodeproj,  // 0=Ux 1=Ujx
    float* __restrict__ xn)              // (16,12,512)
{
    int b = blockIdx.x;  // 16
    int tid = threadIdx.x;
    const float* Ux = nodeproj;
    const float* Ujx = nodeproj + 98304;
    #pragma unroll
    for (int half = 0; half < 2; half++) {
        int c = tid + half * 256;
        float agg[12];
        #pragma unroll
        for (int j = 0; j < 12; j++) agg[j] = 0.f;
        for (int i = 0; i < 12; i++) {
            float sg[12];
            float m = -1e30f;
            #pragma unroll
            for (int j = 0; j < 12; j++) {
                float e = fe[(b * 144 + i * 12 + j) * 512 + c];
                float sv = 1.f / (1.f + __expf(-e));
                sg[j] = sv;
                m = fmaxf(m, sv);
            }
            float ssum = 0.f;
            #pragma unroll
            for (int j = 0; j < 12; j++) { float evv = __expf(sg[j] - m); sg[j] = evv; ssum += evv; }
            float w = Ujx[(b * 12 + i) * 512 + c] / ssum;
            #pragma unroll
            for (int j = 0; j < 12; j++) agg[j] += sg[j] * w;
        }
        #pragma unroll
        for (int j = 0; j < 12; j++)
            xn[(b * 12 + j) * 512 + c] = Ux[(b * 12 + j) * 512 + c] + agg[j] * (1.f / 12.f);
    }
}

// ============ GNN node update: fv = relu(fv + bn_class(xn)) ============
__global__ __launch_bounds__(256) void gnn_node_kernel(
    const float* __restrict__ xn, float* __restrict__ fv)
{
    int k = blockIdx.x;  // 12
    int tid = threadIdx.x;
    __shared__ float red[256];
    float vals[32];
    float sum = 0.f, sq = 0.f;
    int idx = 0;
    for (int b = 0; b < 16; b++) {
        #pragma unroll
        for (int half = 0; half < 2; half++) {
            int c = tid + half * 256;
            float v = xn[(b * 12 + k) * 512 + c];
            vals[idx++] = v;
            sum += v; sq += v * v;
        }
    }
    red[tid] = sum; __syncthreads();
    for (int t = 128; t > 0; t >>= 1) { if (tid < t) red[tid] += red[tid + t]; __syncthreads(); }
    float tsum = red[0]; __syncthreads();
    red[tid] = sq; __syncthreads();
    for (int t = 128; t > 0; t >>= 1) { if (tid < t) red[tid] += red[tid + t]; __syncthreads(); }
    float tsq = red[0];
    float mu = tsum * (1.f / 8192.f);
    float var = tsq * (1.f / 8192.f) - mu * mu;
    float rs = rsqrtf(var + BN_EPS);
    idx = 0;
    for (int b = 0; b < 16; b++) {
        #pragma unroll
        for (int half = 0; half < 2; half++) {
            int c = tid + half * 256;
            int o = (b * 12 + k) * 512 + c;
            float v = (vals[idx++] - mu) * rs;
            fv[o] = fmaxf(fv[o] + v, 0.f);
        }
    }
}

// ============ gather pairwise features: pairX[0]=edges (B,66,1024), pairX[1]=nodes ============
__global__ __launch_bounds__(256) void pair_gather_kernel(
    const float* __restrict__ fe, const float* __restrict__ fv, float* __restrict__ pairX)
{
    int p = blockIdx.x;  // 66
    int b = blockIdx.y;  // 16
    int tid = threadIdx.x;
    int i = 0, rem = p;
    while (rem >= 11 - i) { rem -= 11 - i; i++; }
    int j = i + 1 + rem;
    float* e_out = pairX + (b * 66 + p) * 1024;
    float* n_out = pairX + 1056 * 1024 + (b * 66 + p) * 1024;
    const float* fe_ij = fe + (b * 144 + i * 12 + j) * 512;
    const float* fe_ji = fe + (b * 144 + j * 12 + i) * 512;
    const float* fv_i = fv + (b * 12 + i) * 512;
    const float* fv_j = fv + (b * 12 + j) * 512;
    #pragma unroll
    for (int half = 0; half < 2; half++) {
        int c = tid + half * 256;
        e_out[c] = fe_ij[c];
        e_out[512 + c] = fe_ji[c];
        n_out[c] = fv_i[c];
        n_out[512 + c] = fv_j[c];
    }
}

// ============ MLP layer 3 (Cout=4) ============
__global__ __launch_bounds__(256) void mlp3_kernel(
    const float* __restrict__ X,   // [2][1056][256]
    const float* __restrict__ w3,  // [2][4][256]
    const float* __restrict__ b3,  // [2][4]
    float* __restrict__ Y)         // [2][1056][4]
{
    int idx = blockIdx.x * 256 + threadIdx.x;  // 8448
    if (idx >= 8448) return;
    int o = idx & 3;
    int r = (idx >> 2) % 1056;
    int m = idx / (4 * 1056);
    const float* x = X + (m * 1056 + r) * 256;
    const float* w = w3 + (m * 4 + o) * 256;
    float s = b3[m * 4 + o];
    #pragma unroll 8
    for (int c = 0; c < 256; c++) s += x[c] * w[c];
    Y[idx] = s;
}

// ============ final: out = concat(ed,nd) @ final_w^T + final_b ============
__global__ __launch_bounds__(256) void final_kernel(
    const float* __restrict__ mid3,  // [2][1056][4]
    const float* __restrict__ fw,    // (4,8)
    const float* __restrict__ fb,    // (4)
    float* __restrict__ out)         // (1056,4)
{
    int idx = blockIdx.x * 256 + threadIdx.x;  // 4224
    if (idx >= 4224) return;
    int o = idx & 3;
    int r = idx >> 2;
    const float* ed = mid3 + r * 4;
    const float* nd = mid3 + 1056 * 4 + r * 4;
    float s = fb[o];
    #pragma unroll
    for (int q = 0; q < 4; q++) s += ed[q] * fw[o * 8 + q];
    #pragma unroll
    for (int q = 0; q < 4; q++) s += nd[q] * fw[o * 8 + 4 + q];
    out[idx] = s;
}

extern "C" void kernel_launch(void* const* d_in, const int* in_sizes, int n_in,
                              void* d_out, int out_size, void* d_ws, size_t ws_size,
                              hipStream_t stream)
{
    const float* x      = (const float*)d_in[0];
    const float* cls_w  = (const float*)d_in[1];
    const float* cls_b  = (const float*)d_in[2];
    const float* qw     = (const float*)d_in[3];
    const float* qb     = (const float*)d_in[4];
    const float* kw     = (const float*)d_in[5];
    const float* kb     = (const float*)d_in[6];
    const float* vw     = (const float*)d_in[7];
    const float* vb     = (const float*)d_in[8];
    const float* ep_w   = (const float*)d_in[9];
    const float* ep_b   = (const float*)d_in[10];
    const float* gnn_w  = (const float*)d_in[11];
    const float* mlp_w1 = (const float*)d_in[12];
    const float* mlp_b1 = (const float*)d_in[13];
    const float* mlp_w2 = (const float*)d_in[14];
    const float* mlp_b2 = (const float*)d_in[15];
    const float* mlp_w3 = (const float*)d_in[16];
    const float* mlp_b3 = (const float*)d_in[17];
    const float* fin_w  = (const float*)d_in[18];
    const float* fin_b  = (const float*)d_in[19];
    float* out = (float*)d_out;
    float* ws = (float*)d_ws;

    // ---- workspace layout (floats), ~71.5 MiB total ----
    float* A     = ws;               // 4816896 : h/f_u (k,b,n,512) -> later q2(0..) + k2(+2408448)
    float* q1b   = A + 4816896;      // 2408448 : q1 (k,b,n,256)
    float* k1b   = q1b + 2408448;    // 200704  : k1 (b,n,256)
    float* v1b   = k1b + 200704;     // 401408  : v1 (b,n,512)
    float* Bb    = v1b + 401408;     // 4816896 : feat (k,b,n,512) -> later w2v
    float* Cb    = Bb + 4816896;     // 4816896 : v2 -> gnn temps -> pair temps
    float* fv    = Cb + 4816896;     // 98304   : f_v (b,k,512)
    float* bn1m  = fv + 98304;       // 6144
    float* bn1r  = bn1m + 6144;      // 6144
    float* fe    = bn1r + 6144;      // 1179648 : fe_raw then f_e (b,s,512)
    float* stats = fe + 1179648;     // 288

    float* q2b = A;
    float* k2b = A + 2408448;
    float* v2b = Cb;
    float* w2v = Bb;

    // GNN temps in Cb
    float* nodeproj = Cb;            // [4][16][12][512] = 393216
    float* eE       = Cb + 393216;   // 1179648
    float* xn       = Cb + 1572864;  // 98304
    // pair temps in Cb (GNN temps dead)
    float* pairX = Cb;               // 2162688
    float* mid1  = Cb + 2162688;     // 1081344
    float* mid2  = Cb + 3244032;     // 540672
    float* mid3  = Cb + 3784704;     // 8448

    // 1. h[k,b,n,o] = x @ cls_w[k]^T + cls_b[k]
    mfma_linear_kernel<<<dim3(8, 13, 12), 256, 0, stream>>>(x, 0, cls_w, 262144, cls_b, 512,
                                                            A, 401408, 784, 512, 512, 0);
    // 2-3. BN over (b,n) per (k,o); f_u=relu(bn(h)) in place; f_v = mean_n
    bn1_stats_kernel<<<12, 256, 0, stream>>>(A, bn1m, bn1r);
    fu_fv_kernel<<<dim3(16, 12), 256, 0, stream>>>(A, bn1m, bn1r, fv);
    // 4. q1 = f_u @ qw0^T + qb0
    mfma_linear_kernel<<<dim3(4, 147, 1), 256, 0, stream>>>(A, 0, qw, 0, qb, 0,
                                                            q1b, 0, 9408, 512, 256, 0);
    // 5-6. k1/v1 from x (shared across classes)
    mfma_linear_kernel<<<dim3(4, 13, 1), 256, 0, stream>>>(x, 0, kw, 0, kb, 0,
                                                           k1b, 0, 784, 512, 256, 0);
    mfma_linear_kernel<<<dim3(8, 13, 1), 256, 0, stream>>>(x, 0, vw, 0, vb, 0,
                                                           v1b, 0, 784, 512, 512, 0);
    // 7. feat = attn1
    attn1_kernel<<<dim3(16, 12), 256, 0, stream>>>(q1b, k1b, v1b, Bb);
    // 8-10. q2/k2/v2 from feat (weights set [1])
    mfma_linear_kernel<<<dim3(4, 147, 1), 256, 0, stream>>>(Bb, 0, qw + 131072, 0, qb + 256, 0,
                                                            q2b, 0, 9408, 512, 256, 0);
    mfma_linear_kernel<<<dim3(4, 147, 1), 256, 0, stream>>>(Bb, 0, kw + 131072, 0, kb + 256, 0,
                                                            k2b, 0, 9408, 512, 256, 0);
    mfma_linear_kernel<<<dim3(8, 147, 1), 256, 0, stream>>>(Bb, 0, vw + 262144, 0, vb + 512, 0,
                                                            v2b, 0, 9408, 512, 512, 0);
    // 11. w2v = v2 @ ep_w^T  (ep hoisted through attention)
    mfma_linear_kernel<<<dim3(8, 147, 1), 256, 0, stream>>>(v2b, 0, ep_w, 0, nullptr, 0,
                                                            w2v, 0, 9408, 512, 512, 0);
    // 12-14. fused attn2 + edge BN stats + finalize -> f_e
    hipMemsetAsync(stats, 0, 288 * sizeof(float), stream);
    attn2_kernel<<<dim3(16, 12, 12), 256, 0, stream>>>(q2b, k2b, w2v, ep_b, fe, stats);
    edge_fin_kernel<<<144, 256, 0, stream>>>(stats, fe);

    // 15-16. two GCN blocks
    for (int blk = 0; blk < 2; blk++) {
        const float* gw = gnn_w + blk * 5 * 262144;  // U,V,A,B,E
        mfma_linear_kernel<<<dim3(8, 3, 4), 256, 0, stream>>>(fv, 0, gw, 262144, nullptr, 0,
                                                              nodeproj, 98304, 192, 512, 512, 0);
        mfma_linear_kernel<<<dim3(8, 36, 1), 256, 0, stream>>>(fe, 0, gw + 4 * 262144, 0, nullptr, 0,
                                                               eE, 0, 2304, 512, 512, 0);
        gnn_edge_kernel<<<144, 256, 0, stream>>>(nodeproj, eE, fe);
        gnn_agg_kernel<<<16, 256, 0, stream>>>(fe, nodeproj, xn);
        gnn_node_kernel<<<12, 256, 0, stream>>>(xn, fv);
    }

    // 17. pairwise gather
    pair_gather_kernel<<<dim3(66, 16), 256, 0, stream>>>(fe, fv, pairX);
    // 18-19. MLP layers 1-2 (edge head m=0, node head m=1)
    mfma_linear_kernel<<<dim3(8, 17, 2), 256, 0, stream>>>(pairX, 1081344, mlp_w1, 524288, mlp_b1, 512,
                                                           mid1, 540672, 1056, 1024, 512, 1);
    mfma_linear_kernel<<<dim3(4, 17, 2), 256, 0, stream>>>(mid1, 540672, mlp_w2, 131072, mlp_b2, 256,
                                                           mid2, 270336, 1056, 512, 256, 1);
    // 20. MLP layer 3
    mlp3_kernel<<<33, 256, 0, stream>>>(mid2, mlp_w3, mlp_b3, mid3);
    // 21. final head
    final_kernel<<<17, 256, 0, stream>>>(mid3, fin_w, fin_b, out);
}

// Round 6
// 793.594 us; speedup vs baseline: 3.9381x; 1.3056x over previous
//
#include <hip/hip_runtime.h>

#define BN_EPS 1e-5f

typedef float f32x4 __attribute__((ext_vector_type(4)));
typedef short s16x8 __attribute__((ext_vector_type(8)));

__device__ __forceinline__ short f2bf(float f) {
    unsigned u = __builtin_bit_cast(unsigned, f);
    u = (u + 0x7fffu + ((u >> 16) & 1u)) >> 16;   // RNE
    return (short)u;
}

// ============ MFMA bf16 linear: Y = act(X @ W^T + b), fp32 in ============
// OMODE 0: fp32 out row-major. 1: bf16 out row-major. 2: bf16 out, transposed
// per-49-row tile -> [tile][Cout=512][64] (keys padded to 64; pad pre-zeroed by host memset).
template<int OMODE>
__global__ __launch_bounds__(256) void mfma_linear_kernel(
    const float* __restrict__ X, int Xstride,
    const float* __restrict__ W, int Wstride,
    const float* __restrict__ bias, int bstride,
    void* __restrict__ Yv, int Ystride,
    int R, int Cin, int Cout, int relu)
{
    const int mat = blockIdx.z;
    X += (size_t)mat * Xstride;
    W += (size_t)mat * Wstride;
    const float* bp = bias ? bias + mat * bstride : nullptr;
    float* Yf = (float*)Yv + (size_t)mat * Ystride;
    short* Ys = (short*)Yv + (size_t)mat * Ystride;

    const int r0 = blockIdx.y * 64;
    const int o0 = blockIdx.x * 64;

    __shared__ short As[64 * 40];   // 80B row stride: 20 banks, 2-way alias = free
    __shared__ short Bs[64 * 40];

    const int tid = threadIdx.x;
    const int lane = tid & 63;
    const int wave = tid >> 6;
    const int wr = wave >> 1, wc = wave & 1;
    const int l15 = lane & 15;
    const int lk = lane >> 4;

    const int trow = tid >> 2;
    const int tseg = (tid & 3) * 8;

    f32x4 acc[2][2] = {};

    const int arow = r0 + trow;
    const bool aok = arow < R;
    const float* xrow = X + (size_t)arow * Cin + tseg;
    const float* wrow = W + (size_t)(o0 + trow) * Cin + tseg;

    for (int k0 = 0; k0 < Cin; k0 += 32) {
        float4 a0 = {}, a1 = {};
        if (aok) {
            a0 = *reinterpret_cast<const float4*>(xrow + k0);
            a1 = *reinterpret_cast<const float4*>(xrow + k0 + 4);
        }
        float4 b0 = *reinterpret_cast<const float4*>(wrow + k0);
        float4 b1 = *reinterpret_cast<const float4*>(wrow + k0 + 4);
        s16x8 av, bv;
        av[0] = f2bf(a0.x); av[1] = f2bf(a0.y); av[2] = f2bf(a0.z); av[3] = f2bf(a0.w);
        av[4] = f2bf(a1.x); av[5] = f2bf(a1.y); av[6] = f2bf(a1.z); av[7] = f2bf(a1.w);
        bv[0] = f2bf(b0.x); bv[1] = f2bf(b0.y); bv[2] = f2bf(b0.z); bv[3] = f2bf(b0.w);
        bv[4] = f2bf(b1.x); bv[5] = f2bf(b1.y); bv[6] = f2bf(b1.z); bv[7] = f2bf(b1.w);
        *reinterpret_cast<s16x8*>(&As[trow * 40 + tseg]) = av;
        *reinterpret_cast<s16x8*>(&Bs[trow * 40 + tseg]) = bv;
        __syncthreads();

        s16x8 af[2], bf[2];
        #pragma unroll
        for (int mi = 0; mi < 2; mi++)
            af[mi] = *reinterpret_cast<const s16x8*>(&As[(wr * 32 + mi * 16 + l15) * 40 + lk * 8]);
        #pragma unroll
        for (int ni = 0; ni < 2; ni++)
            bf[ni] = *reinterpret_cast<const s16x8*>(&Bs[(wc * 32 + ni * 16 + l15) * 40 + lk * 8]);
        #pragma unroll
        for (int mi = 0; mi < 2; mi++)
            #pragma unroll
            for (int ni = 0; ni < 2; ni++)
                acc[mi][ni] = __builtin_amdgcn_mfma_f32_16x16x32_bf16(af[mi], bf[ni], acc[mi][ni], 0, 0, 0);
        __syncthreads();
    }

    #pragma unroll
    for (int mi = 0; mi < 2; mi++) {
        #pragma unroll
        for (int ni = 0; ni < 2; ni++) {
            int col = o0 + wc * 32 + ni * 16 + l15;
            int row0 = r0 + wr * 32 + mi * 16 + lk * 4;
            float bb = bp ? bp[col] : 0.f;
            #pragma unroll
            for (int r = 0; r < 4; r++) {
                int row = row0 + r;
                if (row < R) {
                    float v = acc[mi][ni][r] + bb;
                    if (relu) v = fmaxf(v, 0.f);
                    if (OMODE == 0) {
                        Yf[(size_t)row * Cout + col] = v;
                    } else if (OMODE == 1) {
                        Ys[(size_t)row * Cout + col] = f2bf(v);
                    } else {
                        int t = row / 49, n = row - t * 49;
                        Ys[((size_t)t * 512 + col) * 64 + n] = f2bf(v);
                    }
                }
            }
        }
    }
}

// ============ BN stats for h: per (k,o) over (b,n)=784 ============
__global__ __launch_bounds__(256) void bn1_stats_kernel(
    const float* __restrict__ h, float* __restrict__ mean, float* __restrict__ rstd)
{
    int k = blockIdx.x;
    int tid = threadIdx.x;
    #pragma unroll
    for (int half = 0; half < 2; half++) {
        int o = tid + half * 256;
        const float* base = h + k * 401408 + o;
        float s = 0.f, sq = 0.f;
        #pragma unroll 4
        for (int bn = 0; bn < 784; bn++) {
            float v = base[bn * 512];
            s += v; sq += v * v;
        }
        float mu = s * (1.f / 784.f);
        float var = sq * (1.f / 784.f) - mu * mu;
        mean[k * 512 + o] = mu;
        rstd[k * 512 + o] = rsqrtf(var + BN_EPS);
    }
}

// ============ f_u = relu(bn(h)) in place; f_v = mean_n f_u ============
__global__ __launch_bounds__(256) void fu_fv_kernel(
    float* __restrict__ h, const float* __restrict__ mean,
    const float* __restrict__ rstd, float* __restrict__ f_v)
{
    int b = blockIdx.x;
    int k = blockIdx.y;
    int tid = threadIdx.x;
    #pragma unroll
    for (int half = 0; half < 2; half++) {
        int o = tid + half * 256;
        float mu = mean[k * 512 + o], rs = rstd[k * 512 + o];
        float* base = h + (k * 16 + b) * 49 * 512 + o;
        float acc = 0.f;
        #pragma unroll 7
        for (int n = 0; n < 49; n++) {
            float v = (base[n * 512] - mu) * rs;
            v = fmaxf(v, 0.f);
            base[n * 512] = v;
            acc += v;
        }
        f_v[(b * 12 + k) * 512 + o] = acc * (1.f / 49.f);
    }
}

// ============ attn1 (fp32 VALU; tile L2-resident) ============
__global__ __launch_bounds__(256) void attn1_kernel(
    const float* __restrict__ q1,  // (12,16,49,256)
    const float* __restrict__ k1,  // (16,49,256)
    const float* __restrict__ v1,  // (16,49,512)
    float* __restrict__ feat)      // (12,16,49,512)
{
    int b = blockIdx.x;
    int k = blockIdx.y;
    __shared__ float ks[49 * 260];
    __shared__ float Pt[49 * 56];
    int tid = threadIdx.x;
    const float* kb = k1 + b * 49 * 256;
    for (int e = tid; e < 49 * 256; e += 256) ks[(e >> 8) * 260 + (e & 255)] = kb[e];
    __syncthreads();
    const float* qb = q1 + (k * 16 + b) * 49 * 256;
    for (int e = tid; e < 49 * 49; e += 256) {
        int qi = e / 49, kj = e - qi * 49;
        const float4* q4 = reinterpret_cast<const float4*>(qb + qi * 256);
        const float4* k4 = reinterpret_cast<const float4*>(ks + kj * 260);
        float s = 0.f;
        #pragma unroll 8
        for (int d = 0; d < 64; d++) {
            float4 a = q4[d], c = k4[d];
            s += a.x * c.x + a.y * c.y + a.z * c.z + a.w * c.w;
        }
        Pt[kj * 56 + qi] = s * 0.0625f;
    }
    __syncthreads();
    if (tid < 196) {
        int qi = tid >> 2, sub = tid & 3;
        float ev[13];
        float m = -1e30f;
        #pragma unroll 13
        for (int t = 0; t < 13; t++) {
            int j = sub + t * 4;
            ev[t] = (j < 49) ? Pt[j * 56 + qi] : -1e30f;
            m = fmaxf(m, ev[t]);
        }
        m = fmaxf(m, __shfl_xor(m, 1));
        m = fmaxf(m, __shfl_xor(m, 2));
        float s = 0.f;
        #pragma unroll 13
        for (int t = 0; t < 13; t++) { ev[t] = __expf(ev[t] - m); s += ev[t]; }
        s += __shfl_xor(s, 1);
        s += __shfl_xor(s, 2);
        float inv = 1.f / s;
        #pragma unroll 13
        for (int t = 0; t < 13; t++) {
            int j = sub + t * 4;
            if (j < 49) Pt[j * 56 + qi] = ev[t] * inv;
        }
    }
    __syncthreads();
    const float* vb = v1 + b * 49 * 512;
    float* fb = feat + (k * 16 + b) * 49 * 512;
    for (int qc = 0; qc < 49; qc += 8) {
        int nq = 49 - qc; if (nq > 8) nq = 8;
        float a0[8] = {}, a1[8] = {};
        for (int kj = 0; kj < 49; kj++) {
            float v0 = vb[kj * 512 + tid];
            float v1v = vb[kj * 512 + 256 + tid];
            const float4* pr = reinterpret_cast<const float4*>(&Pt[kj * 56 + qc]);
            float4 p0 = pr[0], p1 = pr[1];
            a0[0] += p0.x * v0; a1[0] += p0.x * v1v;
            a0[1] += p0.y * v0; a1[1] += p0.y * v1v;
            a0[2] += p0.z * v0; a1[2] += p0.z * v1v;
            a0[3] += p0.w * v0; a1[3] += p0.w * v1v;
            a0[4] += p1.x * v0; a1[4] += p1.x * v1v;
            a0[5] += p1.y * v0; a1[5] += p1.y * v1v;
            a0[6] += p1.z * v0; a1[6] += p1.z * v1v;
            a0[7] += p1.w * v0; a1[7] += p1.w * v1v;
        }
        #pragma unroll 8
        for (int u = 0; u < 8; u++) {
            if (u < nq) {
                fb[(qc + u) * 512 + tid] = a0[u];
                fb[(qc + u) * 512 + 256 + tid] = a1[u];
            }
        }
    }
}

// ============ attn2 MFMA: per (b,i,j) block, bf16 inputs, no input staging ============
// q2/k2: bf16 (12,16,49,256). w2vT: bf16 (12,16) tiles of [512][64] (pad keys zeroed).
// S = q2[j] @ k2[i]^T / 16 ; P = softmax_row(S) ; O = P @ V ; emit colmeans + stats.
__global__ __launch_bounds__(256) void attn2_mfma_kernel(
    const short* __restrict__ q2,
    const short* __restrict__ k2,
    const short* __restrict__ w2vT,
    const float* __restrict__ ep_b,
    float* __restrict__ fe_raw,     // (16,144,512)
    float* __restrict__ stats)      // (144,2)
{
    const int b = blockIdx.x, i = blockIdx.y, j = blockIdx.z;
    __shared__ float S[64 * 68];    // fp32 scores [q][key]
    __shared__ short P[64 * 88];    // bf16 probs  [q][key], 16B-aligned rows
    __shared__ float red[256];
    const int tid = threadIdx.x;
    const int lane = tid & 63, w = tid >> 6;
    const int l15 = lane & 15, lk = lane >> 4;

    const short* qb = q2 + (size_t)((j * 16 + b) * 49) * 256;
    const short* kb = k2 + (size_t)((i * 16 + b) * 49) * 256;

    // ---- QK^T: wave w computes S rows w*16..+15, all 64 key-cols, K=256 ----
    {
        int qrow = w * 16 + l15; if (qrow > 48) qrow = 48;   // clamp pad rows
        f32x4 sacc[4] = {};
        #pragma unroll
        for (int ks = 0; ks < 8; ks++) {
            s16x8 aq = *reinterpret_cast<const s16x8*>(qb + (size_t)qrow * 256 + ks * 32 + lk * 8);
            #pragma unroll
            for (int ni = 0; ni < 4; ni++) {
                int krow = ni * 16 + l15; if (krow > 48) krow = 48;
                s16x8 bk = *reinterpret_cast<const s16x8*>(kb + (size_t)krow * 256 + ks * 32 + lk * 8);
                sacc[ni] = __builtin_amdgcn_mfma_f32_16x16x32_bf16(aq, bk, sacc[ni], 0, 0, 0);
            }
        }
        #pragma unroll
        for (int ni = 0; ni < 4; ni++)
            #pragma unroll
            for (int r = 0; r < 4; r++)
                S[(w * 16 + lk * 4 + r) * 68 + ni * 16 + l15] = sacc[ni][r] * 0.0625f;
    }
    __syncthreads();

    // ---- softmax rows 0..48 over keys 0..48; P bf16 with pads zeroed ----
    if (tid < 196) {
        int qi = tid >> 2, sub = tid & 3;
        float ev[13];
        float m = -1e30f;
        #pragma unroll 13
        for (int t = 0; t < 13; t++) {
            int kk = sub + t * 4;
            ev[t] = (kk < 49) ? S[qi * 68 + kk] : -1e30f;
            m = fmaxf(m, ev[t]);
        }
        m = fmaxf(m, __shfl_xor(m, 1));
        m = fmaxf(m, __shfl_xor(m, 2));
        float s = 0.f;
        #pragma unroll 13
        for (int t = 0; t < 13; t++) { ev[t] = __expf(ev[t] - m); s += ev[t]; }
        s += __shfl_xor(s, 1);
        s += __shfl_xor(s, 2);
        float inv = 1.f / s;
        #pragma unroll 13
        for (int t = 0; t < 13; t++) {
            int kk = sub + t * 4;
            if (kk < 49) P[qi * 88 + kk] = f2bf(ev[t] * inv);
        }
        for (int kk = 49 + sub; kk < 64; kk += 4) P[qi * 88 + kk] = 0;   // zero pad keys
    } else {
        int t2 = tid - 196;                                               // zero pad rows
        for (int idx = t2; idx < 15 * 64; idx += 60) {
            int rr = idx / 64, cc = idx - rr * 64;
            P[(49 + rr) * 88 + cc] = 0;
        }
    }
    __syncthreads();

    // ---- PV: wave w owns 64 channels per half (2 halves of 256) ----
    const short* vt = w2vT + (size_t)((i * 16 + b) * 512) * 64;
    const int slot = i * 12 + j;
    float tot = 0.f, csq = 0.f;
    #pragma unroll
    for (int half = 0; half < 2; half++) {
        const int cb = half * 256 + w * 64;
        f32x4 pac[4][4] = {};
        #pragma unroll
        for (int ks = 0; ks < 2; ks++) {
            s16x8 bv[4];
            #pragma unroll
            for (int ni = 0; ni < 4; ni++) {
                int ch = cb + ni * 16 + l15;
                bv[ni] = *reinterpret_cast<const s16x8*>(vt + (size_t)ch * 64 + ks * 32 + lk * 8);
            }
            #pragma unroll
            for (int mi = 0; mi < 4; mi++) {
                s16x8 ap = *reinterpret_cast<const s16x8*>(&P[(mi * 16 + l15) * 88 + ks * 32 + lk * 8]);
                #pragma unroll
                for (int ni = 0; ni < 4; ni++)
                    pac[mi][ni] = __builtin_amdgcn_mfma_f32_16x16x32_bf16(ap, bv[ni], pac[mi][ni], 0, 0, 0);
            }
        }
        // epilogue: per-col sums over valid rows, stats partials
        #pragma unroll
        for (int ni = 0; ni < 4; ni++) {
            int col = cb + ni * 16 + l15;
            float bias = ep_b[col];
            float cs = 0.f;
            #pragma unroll
            for (int mi = 0; mi < 4; mi++) {
                #pragma unroll
                for (int r = 0; r < 4; r++) {
                    int row = mi * 16 + lk * 4 + r;
                    if (row < 49) {
                        float sv = pac[mi][ni][r] + bias;
                        cs += sv; csq += sv * sv;
                    }
                }
            }
            tot += cs;
            cs += __shfl_xor(cs, 16);
            cs += __shfl_xor(cs, 32);
            if (lk == 0)
                fe_raw[((size_t)b * 144 + slot) * 512 + col] = cs * (1.f / 49.f);
        }
    }
    // block-reduce tot & csq -> atomics
    red[tid] = tot; __syncthreads();
    for (int t = 128; t > 0; t >>= 1) { if (tid < t) red[tid] += red[tid + t]; __syncthreads(); }
    if (tid == 0) atomicAdd(&stats[slot * 2], red[0]);
    __syncthreads();
    red[tid] = csq; __syncthreads();
    for (int t = 128; t > 0; t >>= 1) { if (tid < t) red[tid] += red[tid + t]; __syncthreads(); }
    if (tid == 0) atomicAdd(&stats[slot * 2 + 1], red[0]);
}

// ============ finalize edge BN ============
__global__ __launch_bounds__(256) void edge_fin_kernel(
    const float* __restrict__ stats, float* __restrict__ fe)
{
    int s = blockIdx.x;
    const float inv = 1.f / 401408.f;
    float mu = stats[s * 2] * inv;
    float var = stats[s * 2 + 1] * inv - mu * mu;
    float rs = rsqrtf(var + BN_EPS);
    int tid = threadIdx.x;
    for (int b = 0; b < 16; b++) {
        float* p = fe + (b * 144 + s) * 512;
        #pragma unroll
        for (int half = 0; half < 2; half++) {
            int c = tid + half * 256;
            p[c] = (p[c] - mu) * rs;
        }
    }
}

// ============ GNN edge update ============
__global__ __launch_bounds__(256) void gnn_edge_kernel(
    const float* __restrict__ nodeproj,
    const float* __restrict__ eE,
    float* __restrict__ fe)
{
    int s = blockIdx.x;
    int i = s / 12, j = s - i * 12;
    int tid = threadIdx.x;
    const float* Vix = nodeproj + 2 * 98304;
    const float* Vjx = nodeproj + 3 * 98304;
    __shared__ float red[256];
    float msg[32];
    float sum = 0.f, sq = 0.f;
    int idx = 0;
    for (int b = 0; b < 16; b++) {
        #pragma unroll
        for (int half = 0; half < 2; half++) {
            int c = tid + half * 256;
            float v = Vjx[(b * 12 + i) * 512 + c] + Vix[(b * 12 + j) * 512 + c]
                    + eE[(b * 144 + s) * 512 + c];
            msg[idx++] = v;
            sum += v; sq += v * v;
        }
    }
    red[tid] = sum; __syncthreads();
    for (int t = 128; t > 0; t >>= 1) { if (tid < t) red[tid] += red[tid + t]; __syncthreads(); }
    float tsum = red[0]; __syncthreads();
    red[tid] = sq; __syncthreads();
    for (int t = 128; t > 0; t >>= 1) { if (tid < t) red[tid] += red[tid + t]; __syncthreads(); }
    float tsq = red[0];
    float mu = tsum * (1.f / 8192.f);
    float var = tsq * (1.f / 8192.f) - mu * mu;
    float rs = rsqrtf(var + BN_EPS);
    idx = 0;
    for (int b = 0; b < 16; b++) {
        #pragma unroll
        for (int half = 0; half < 2; half++) {
            int c = tid + half * 256;
            float v = fmaxf((msg[idx++] - mu) * rs, 0.f);
            fe[(b * 144 + s) * 512 + c] += v;
        }
    }
}

// ============ GNN aggregation ============
__global__ __launch_bounds__(256) void gnn_agg_kernel(
    const float* __restrict__ fe,
    const float* __restrict__ nodeproj,
    float* __restrict__ xn)
{
    int b = blockIdx.x;
    int tid = threadIdx.x;
    const float* Ux = nodeproj;
    const float* Ujx = nodeproj + 98304;
    #pragma unroll
    for (int half = 0; half < 2; half++) {
        int c = tid + half * 256;
        float agg[12];
        #pragma unroll
        for (int j = 0; j < 12; j++) agg[j] = 0.f;
        for (int i = 0; i < 12; i++) {
            float sg[12];
            float m = -1e30f;
            #pragma unroll
            for (int j = 0; j < 12; j++) {
                float e = fe[(b * 144 + i * 12 + j) * 512 + c];
                float sv = 1.f / (1.f + __expf(-e));
                sg[j] = sv;
                m = fmaxf(m, sv);
            }
            float ssum = 0.f;
            #pragma unroll
            for (int j = 0; j < 12; j++) { float evv = __expf(sg[j] - m); sg[j] = evv; ssum += evv; }
            float wgt = Ujx[(b * 12 + i) * 512 + c] / ssum;
            #pragma unroll
            for (int j = 0; j < 12; j++) agg[j] += sg[j] * wgt;
        }
        #pragma unroll
        for (int j = 0; j < 12; j++)
            xn[(b * 12 + j) * 512 + c] = Ux[(b * 12 + j) * 512 + c] + agg[j] * (1.f / 12.f);
    }
}

// ============ GNN node update ============
__global__ __launch_bounds__(256) void gnn_node_kernel(
    const float* __restrict__ xn, float* __restrict__ fv)
{
    int k = blockIdx.x;
    int tid = threadIdx.x;
    __shared__ float red[256];
    float vals[32];
    float sum = 0.f, sq = 0.f;
    int idx = 0;
    for (int b = 0; b < 16; b++) {
        #pragma unroll
        for (int half = 0; half < 2; half++) {
            int c = tid + half * 256;
            float v = xn[(b * 12 + k) * 512 + c];
            vals[idx++] = v;
            sum += v; sq += v * v;
        }
    }
    red[tid] = sum; __syncthreads();
    for (int t = 128; t > 0; t >>= 1) { if (tid < t) red[tid] += red[tid + t]; __syncthreads(); }
    float tsum = red[0]; __syncthreads();
    red[tid] = sq; __syncthreads();
    for (int t = 128; t > 0; t >>= 1) { if (tid < t) red[tid] += red[tid + t]; __syncthreads(); }
    float tsq = red[0];
    float mu = tsum * (1.f / 8192.f);
    float var = tsq * (1.f / 8192.f) - mu * mu;
    float rs = rsqrtf(var + BN_EPS);
    idx = 0;
    for (int b = 0; b < 16; b++) {
        #pragma unroll
        for (int half = 0; half < 2; half++) {
            int c = tid + half * 256;
            int o = (b * 12 + k) * 512 + c;
            float v = (vals[idx++] - mu) * rs;
            fv[o] = fmaxf(fv[o] + v, 0.f);
        }
    }
}

// ============ pairwise gather ============
__global__ __launch_bounds__(256) void pair_gather_kernel(
    const float* __restrict__ fe, const float* __restrict__ fv, float* __restrict__ pairX)
{
    int p = blockIdx.x;
    int b = blockIdx.y;
    int tid = threadIdx.x;
    int i = 0, rem = p;
    while (rem >= 11 - i) { rem -= 11 - i; i++; }
    int j = i + 1 + rem;
    float* e_out = pairX + (b * 66 + p) * 1024;
    float* n_out = pairX + 1056 * 1024 + (b * 66 + p) * 1024;
    const float* fe_ij = fe + (b * 144 + i * 12 + j) * 512;
    const float* fe_ji = fe + (b * 144 + j * 12 + i) * 512;
    const float* fv_i = fv + (b * 12 + i) * 512;
    const float* fv_j = fv + (b * 12 + j) * 512;
    #pragma unroll
    for (int half = 0; half < 2; half++) {
        int c = tid + half * 256;
        e_out[c] = fe_ij[c];
        e_out[512 + c] = fe_ji[c];
        n_out[c] = fv_i[c];
        n_out[512 + c] = fv_j[c];
    }
}

// ============ MLP layer 3 (Cout=4) ============
__global__ __launch_bounds__(256) void mlp3_kernel(
    const float* __restrict__ X,
    const float* __restrict__ w3,
    const float* __restrict__ b3,
    float* __restrict__ Y)
{
    int idx = blockIdx.x * 256 + threadIdx.x;
    if (idx >= 8448) return;
    int o = idx & 3;
    int r = (idx >> 2) % 1056;
    int m = idx / (4 * 1056);
    const float* x = X + (m * 1056 + r) * 256;
    const float* w = w3 + (m * 4 + o) * 256;
    float s = b3[m * 4 + o];
    #pragma unroll 8
    for (int c = 0; c < 256; c++) s += x[c] * w[c];
    Y[idx] = s;
}

// ============ final head ============
__global__ __launch_bounds__(256) void final_kernel(
    const float* __restrict__ mid3,
    const float* __restrict__ fw,
    const float* __restrict__ fb,
    float* __restrict__ out)
{
    int idx = blockIdx.x * 256 + threadIdx.x;
    if (idx >= 4224) return;
    int o = idx & 3;
    int r = idx >> 2;
    const float* ed = mid3 + r * 4;
    const float* nd = mid3 + 1056 * 4 + r * 4;
    float s = fb[o];
    #pragma unroll
    for (int q = 0; q < 4; q++) s += ed[q] * fw[o * 8 + q];
    #pragma unroll
    for (int q = 0; q < 4; q++) s += nd[q] * fw[o * 8 + 4 + q];
    out[idx] = s;
}

extern "C" void kernel_launch(void* const* d_in, const int* in_sizes, int n_in,
                              void* d_out, int out_size, void* d_ws, size_t ws_size,
                              hipStream_t stream)
{
    const float* x      = (const float*)d_in[0];
    const float* cls_w  = (const float*)d_in[1];
    const float* cls_b  = (const float*)d_in[2];
    const float* qw     = (const float*)d_in[3];
    const float* qb     = (const float*)d_in[4];
    const float* kw     = (const float*)d_in[5];
    const float* kb     = (const float*)d_in[6];
    const float* vw     = (const float*)d_in[7];
    const float* vb     = (const float*)d_in[8];
    const float* ep_w   = (const float*)d_in[9];
    const float* ep_b   = (const float*)d_in[10];
    const float* gnn_w  = (const float*)d_in[11];
    const float* mlp_w1 = (const float*)d_in[12];
    const float* mlp_b1 = (const float*)d_in[13];
    const float* mlp_w2 = (const float*)d_in[14];
    const float* mlp_b2 = (const float*)d_in[15];
    const float* mlp_w3 = (const float*)d_in[16];
    const float* mlp_b3 = (const float*)d_in[17];
    const float* fin_w  = (const float*)d_in[18];
    const float* fin_b  = (const float*)d_in[19];
    float* out = (float*)d_out;
    float* ws = (float*)d_ws;

    // ---- workspace layout (floats), ~75 MiB ----
    float* A     = ws;               // 4816896 : h/f_u ; later q2bf+k2bf (bf16)
    float* q1b   = A + 4816896;      // 2408448
    float* k1b   = q1b + 2408448;    // 200704
    float* v1b   = k1b + 200704;     // 401408
    float* Bb    = v1b + 401408;     // 4816896 : feat ; later w2vT (bf16, 3145728 f)
    float* Cb    = Bb + 4816896;     // 4816896 : v2 -> gnn temps -> pair temps
    float* fv    = Cb + 4816896;     // 98304
    float* bn1m  = fv + 98304;       // 6144
    float* bn1r  = bn1m + 6144;      // 6144
    float* fe    = bn1r + 6144;      // 1179648
    float* stats = fe + 1179648;     // 288

    short* q2bf = (short*)A;                    // (12,16,49,256) bf16
    short* k2bf = (short*)(A + 1204224);        // (12,16,49,256) bf16
    float* v2b  = Cb;                           // (12,16,49,512) fp32
    short* w2vT = (short*)Bb;                   // (12,16,512,64) bf16

    // GNN temps in Cb (after v2 dead)
    float* nodeproj = Cb;            // [4][16][12][512]
    float* eE       = Cb + 393216;
    float* xn       = Cb + 1572864;
    // pair temps in Cb (GNN temps dead)
    float* pairX = Cb;
    float* mid1  = Cb + 2162688;
    float* mid2  = Cb + 3244032;
    float* mid3  = Cb + 3784704;

    // 1. h = x @ cls_w^T + cls_b  (per class)
    mfma_linear_kernel<0><<<dim3(8, 13, 12), 256, 0, stream>>>(x, 0, cls_w, 262144, cls_b, 512,
                                                               A, 401408, 784, 512, 512, 0);
    // 2-3. BN + relu in place; f_v
    bn1_stats_kernel<<<12, 256, 0, stream>>>(A, bn1m, bn1r);
    fu_fv_kernel<<<dim3(16, 12), 256, 0, stream>>>(A, bn1m, bn1r, fv);
    // 4. q1 = f_u @ qw0^T + qb0
    mfma_linear_kernel<0><<<dim3(4, 147, 1), 256, 0, stream>>>(A, 0, qw, 0, qb, 0,
                                                               q1b, 0, 9408, 512, 256, 0);
    // 5-6. k1/v1 from x
    mfma_linear_kernel<0><<<dim3(4, 13, 1), 256, 0, stream>>>(x, 0, kw, 0, kb, 0,
                                                              k1b, 0, 784, 512, 256, 0);
    mfma_linear_kernel<0><<<dim3(8, 13, 1), 256, 0, stream>>>(x, 0, vw, 0, vb, 0,
                                                              v1b, 0, 784, 512, 512, 0);
    // 7. feat = attn1
    attn1_kernel<<<dim3(16, 12), 256, 0, stream>>>(q1b, k1b, v1b, Bb);
    // 8-10. q2/k2 (bf16 out), v2 (fp32) from feat
    mfma_linear_kernel<1><<<dim3(4, 147, 1), 256, 0, stream>>>(Bb, 0, qw + 131072, 0, qb + 256, 0,
                                                               q2bf, 0, 9408, 512, 256, 0);
    mfma_linear_kernel<1><<<dim3(4, 147, 1), 256, 0, stream>>>(Bb, 0, kw + 131072, 0, kb + 256, 0,
                                                               k2bf, 0, 9408, 512, 256, 0);
    mfma_linear_kernel<0><<<dim3(8, 147, 1), 256, 0, stream>>>(Bb, 0, vw + 262144, 0, vb + 512, 0,
                                                               v2b, 0, 9408, 512, 512, 0);
    // 11. w2vT = (v2 @ ep_w^T) transposed per-tile, bf16 (overwrites feat region).
    //     Zero the whole region first so pad key-columns (n=49..63) are deterministic 0
    //     (harness poisons d_ws with 0xAA; Inf/NaN garbage would poison 0*x in PV).
    hipMemsetAsync(w2vT, 0, (size_t)12 * 16 * 512 * 64 * sizeof(short), stream);
    mfma_linear_kernel<2><<<dim3(8, 147, 1), 256, 0, stream>>>(v2b, 0, ep_w, 0, nullptr, 0,
                                                               w2vT, 0, 9408, 512, 512, 0);
    // 12-14. MFMA attn2 + edge BN
    hipMemsetAsync(stats, 0, 288 * sizeof(float), stream);
    attn2_mfma_kernel<<<dim3(16, 12, 12), 256, 0, stream>>>(q2bf, k2bf, w2vT, ep_b, fe, stats);
    edge_fin_kernel<<<144, 256, 0, stream>>>(stats, fe);

    // 15-16. two GCN blocks
    for (int blk = 0; blk < 2; blk++) {
        const float* gw = gnn_w + blk * 5 * 262144;  // U,V,A,B,E
        mfma_linear_kernel<0><<<dim3(8, 3, 4), 256, 0, stream>>>(fv, 0, gw, 262144, nullptr, 0,
                                                                 nodeproj, 98304, 192, 512, 512, 0);
        mfma_linear_kernel<0><<<dim3(8, 36, 1), 256, 0, stream>>>(fe, 0, gw + 4 * 262144, 0, nullptr, 0,
                                                                  eE, 0, 2304, 512, 512, 0);
        gnn_edge_kernel<<<144, 256, 0, stream>>>(nodeproj, eE, fe);
        gnn_agg_kernel<<<16, 256, 0, stream>>>(fe, nodeproj, xn);
        gnn_node_kernel<<<12, 256, 0, stream>>>(xn, fv);
    }

    // 17. pairwise gather
    pair_gather_kernel<<<dim3(66, 16), 256, 0, stream>>>(fe, fv, pairX);
    // 18-19. MLP layers 1-2
    mfma_linear_kernel<0><<<dim3(8, 17, 2), 256, 0, stream>>>(pairX, 1081344, mlp_w1, 524288, mlp_b1, 512,
                                                              mid1, 540672, 1056, 1024, 512, 1);
    mfma_linear_kernel<0><<<dim3(4, 17, 2), 256, 0, stream>>>(mid1, 540672, mlp_w2, 131072, mlp_b2, 256,
                                                              mid2, 270336, 1056, 512, 256, 1);
    // 20. MLP layer 3
    mlp3_kernel<<<33, 256, 0, stream>>>(mid2, mlp_w3, mlp_b3, mid3);
    // 21. final head
    final_kernel<<<17, 256, 0, stream>>>(mid3, fin_w, fin_b, out);
}

// Round 7
// 678.311 us; speedup vs baseline: 4.6074x; 1.1700x over previous
//
#include <hip/hip_runtime.h>

#define BN_EPS 1e-5f

typedef float f32x4 __attribute__((ext_vector_type(4)));
typedef short s16x8 __attribute__((ext_vector_type(8)));

__device__ __forceinline__ short f2bf(float f) {
    unsigned u = __builtin_bit_cast(unsigned, f);
    u = (u + 0x7fffu + ((u >> 16) & 1u)) >> 16;   // RNE
    return (short)u;
}

// ============ MFMA bf16 linear: Y = act(X @ W^T + b), fp32 in ============
// OMODE 0: fp32 out row-major. 1: bf16 out row-major. 2: bf16 out, transposed
// per-49-row tile -> [tile][Cout=512][64] (keys padded to 64; pad pre-zeroed by host memset).
template<int OMODE>
__global__ __launch_bounds__(256) void mfma_linear_kernel(
    const float* __restrict__ X, int Xstride,
    const float* __restrict__ W, int Wstride,
    const float* __restrict__ bias, int bstride,
    void* __restrict__ Yv, int Ystride,
    int R, int Cin, int Cout, int relu)
{
    const int mat = blockIdx.z;
    X += (size_t)mat * Xstride;
    W += (size_t)mat * Wstride;
    const float* bp = bias ? bias + mat * bstride : nullptr;
    float* Yf = (float*)Yv + (size_t)mat * Ystride;
    short* Ys = (short*)Yv + (size_t)mat * Ystride;

    const int r0 = blockIdx.y * 64;
    const int o0 = blockIdx.x * 64;

    __shared__ short As[64 * 40];   // 80B row stride: 20 banks, 2-way alias = free
    __shared__ short Bs[64 * 40];

    const int tid = threadIdx.x;
    const int lane = tid & 63;
    const int wave = tid >> 6;
    const int wr = wave >> 1, wc = wave & 1;
    const int l15 = lane & 15;
    const int lk = lane >> 4;

    const int trow = tid >> 2;
    const int tseg = (tid & 3) * 8;

    f32x4 acc[2][2] = {};

    const int arow = r0 + trow;
    const bool aok = arow < R;
    const float* xrow = X + (size_t)arow * Cin + tseg;
    const float* wrow = W + (size_t)(o0 + trow) * Cin + tseg;

    for (int k0 = 0; k0 < Cin; k0 += 32) {
        float4 a0 = {}, a1 = {};
        if (aok) {
            a0 = *reinterpret_cast<const float4*>(xrow + k0);
            a1 = *reinterpret_cast<const float4*>(xrow + k0 + 4);
        }
        float4 b0 = *reinterpret_cast<const float4*>(wrow + k0);
        float4 b1 = *reinterpret_cast<const float4*>(wrow + k0 + 4);
        s16x8 av, bv;
        av[0] = f2bf(a0.x); av[1] = f2bf(a0.y); av[2] = f2bf(a0.z); av[3] = f2bf(a0.w);
        av[4] = f2bf(a1.x); av[5] = f2bf(a1.y); av[6] = f2bf(a1.z); av[7] = f2bf(a1.w);
        bv[0] = f2bf(b0.x); bv[1] = f2bf(b0.y); bv[2] = f2bf(b0.z); bv[3] = f2bf(b0.w);
        bv[4] = f2bf(b1.x); bv[5] = f2bf(b1.y); bv[6] = f2bf(b1.z); bv[7] = f2bf(b1.w);
        *reinterpret_cast<s16x8*>(&As[trow * 40 + tseg]) = av;
        *reinterpret_cast<s16x8*>(&Bs[trow * 40 + tseg]) = bv;
        __syncthreads();

        s16x8 af[2], bf[2];
        #pragma unroll
        for (int mi = 0; mi < 2; mi++)
            af[mi] = *reinterpret_cast<const s16x8*>(&As[(wr * 32 + mi * 16 + l15) * 40 + lk * 8]);
        #pragma unroll
        for (int ni = 0; ni < 2; ni++)
            bf[ni] = *reinterpret_cast<const s16x8*>(&Bs[(wc * 32 + ni * 16 + l15) * 40 + lk * 8]);
        #pragma unroll
        for (int mi = 0; mi < 2; mi++)
            #pragma unroll
            for (int ni = 0; ni < 2; ni++)
                acc[mi][ni] = __builtin_amdgcn_mfma_f32_16x16x32_bf16(af[mi], bf[ni], acc[mi][ni], 0, 0, 0);
        __syncthreads();
    }

    #pragma unroll
    for (int mi = 0; mi < 2; mi++) {
        #pragma unroll
        for (int ni = 0; ni < 2; ni++) {
            int col = o0 + wc * 32 + ni * 16 + l15;
            int row0 = r0 + wr * 32 + mi * 16 + lk * 4;
            float bb = bp ? bp[col] : 0.f;
            #pragma unroll
            for (int r = 0; r < 4; r++) {
                int row = row0 + r;
                if (row < R) {
                    float v = acc[mi][ni][r] + bb;
                    if (relu) v = fmaxf(v, 0.f);
                    if (OMODE == 0) {
                        Yf[(size_t)row * Cout + col] = v;
                    } else if (OMODE == 1) {
                        Ys[(size_t)row * Cout + col] = f2bf(v);
                    } else {
                        int t = row / 49, n = row - t * 49;
                        Ys[((size_t)t * 512 + col) * 64 + n] = f2bf(v);
                    }
                }
            }
        }
    }
}

// ============ BN1 partial stats: grid (12, 8); atomicAdd (sum, sumsq) per (k,o) ============
__global__ __launch_bounds__(256) void bn1_partial_kernel(
    const float* __restrict__ h, float* __restrict__ bsum, float* __restrict__ bsq)
{
    int k = blockIdx.x;          // class
    int part = blockIdx.y;       // 0..7, rows [part*98, +98)
    int tid = threadIdx.x;
    #pragma unroll
    for (int half = 0; half < 2; half++) {
        int o = tid + half * 256;
        const float* base = h + (size_t)k * 401408 + (size_t)part * 98 * 512 + o;
        float s = 0.f, sq = 0.f;
        #pragma unroll 7
        for (int bn = 0; bn < 98; bn++) {
            float v = base[bn * 512];
            s += v; sq += v * v;
        }
        atomicAdd(&bsum[k * 512 + o], s);
        atomicAdd(&bsq[k * 512 + o], sq);
    }
}

// ============ f_u = relu(bn(h)) in place; f_v = mean_n f_u. mu/rstd from (sum,sq) ============
__global__ __launch_bounds__(256) void fu_fv_kernel(
    float* __restrict__ h, const float* __restrict__ bsum,
    const float* __restrict__ bsq, float* __restrict__ f_v)
{
    int b = blockIdx.x;
    int k = blockIdx.y;
    int tid = threadIdx.x;
    #pragma unroll
    for (int half = 0; half < 2; half++) {
        int o = tid + half * 256;
        float mu = bsum[k * 512 + o] * (1.f / 784.f);
        float var = bsq[k * 512 + o] * (1.f / 784.f) - mu * mu;
        float rs = rsqrtf(var + BN_EPS);
        float* base = h + (size_t)(k * 16 + b) * 49 * 512 + o;
        float acc = 0.f;
        #pragma unroll 7
        for (int n = 0; n < 49; n++) {
            float v = (base[n * 512] - mu) * rs;
            v = fmaxf(v, 0.f);
            base[n * 512] = v;
            acc += v;
        }
        f_v[(b * 12 + k) * 512 + o] = acc * (1.f / 49.f);
    }
}

// ============ attn1 (fp32 VALU; tile L2-resident) ============
__global__ __launch_bounds__(256) void attn1_kernel(
    const float* __restrict__ q1,  // (12,16,49,256)
    const float* __restrict__ k1,  // (16,49,256)
    const float* __restrict__ v1,  // (16,49,512)
    float* __restrict__ feat)      // (12,16,49,512)
{
    int b = blockIdx.x;
    int k = blockIdx.y;
    __shared__ float ks[49 * 260];
    __shared__ float Pt[49 * 56];
    int tid = threadIdx.x;
    const float* kb = k1 + b * 49 * 256;
    for (int e = tid; e < 49 * 256; e += 256) ks[(e >> 8) * 260 + (e & 255)] = kb[e];
    __syncthreads();
    const float* qb = q1 + (k * 16 + b) * 49 * 256;
    for (int e = tid; e < 49 * 49; e += 256) {
        int qi = e / 49, kj = e - qi * 49;
        const float4* q4 = reinterpret_cast<const float4*>(qb + qi * 256);
        const float4* k4 = reinterpret_cast<const float4*>(ks + kj * 260);
        float s = 0.f;
        #pragma unroll 8
        for (int d = 0; d < 64; d++) {
            float4 a = q4[d], c = k4[d];
            s += a.x * c.x + a.y * c.y + a.z * c.z + a.w * c.w;
        }
        Pt[kj * 56 + qi] = s * 0.0625f;
    }
    __syncthreads();
    if (tid < 196) {
        int qi = tid >> 2, sub = tid & 3;
        float ev[13];
        float m = -1e30f;
        #pragma unroll 13
        for (int t = 0; t < 13; t++) {
            int j = sub + t * 4;
            ev[t] = (j < 49) ? Pt[j * 56 + qi] : -1e30f;
            m = fmaxf(m, ev[t]);
        }
        m = fmaxf(m, __shfl_xor(m, 1));
        m = fmaxf(m, __shfl_xor(m, 2));
        float s = 0.f;
        #pragma unroll 13
        for (int t = 0; t < 13; t++) { ev[t] = __expf(ev[t] - m); s += ev[t]; }
        s += __shfl_xor(s, 1);
        s += __shfl_xor(s, 2);
        float inv = 1.f / s;
        #pragma unroll 13
        for (int t = 0; t < 13; t++) {
            int j = sub + t * 4;
            if (j < 49) Pt[j * 56 + qi] = ev[t] * inv;
        }
    }
    __syncthreads();
    const float* vb = v1 + b * 49 * 512;
    float* fb = feat + (k * 16 + b) * 49 * 512;
    for (int qc = 0; qc < 49; qc += 8) {
        int nq = 49 - qc; if (nq > 8) nq = 8;
        float a0[8] = {}, a1[8] = {};
        for (int kj = 0; kj < 49; kj++) {
            float v0 = vb[kj * 512 + tid];
            float v1v = vb[kj * 512 + 256 + tid];
            const float4* pr = reinterpret_cast<const float4*>(&Pt[kj * 56 + qc]);
            float4 p0 = pr[0], p1 = pr[1];
            a0[0] += p0.x * v0; a1[0] += p0.x * v1v;
            a0[1] += p0.y * v0; a1[1] += p0.y * v1v;
            a0[2] += p0.z * v0; a1[2] += p0.z * v1v;
            a0[3] += p0.w * v0; a1[3] += p0.w * v1v;
            a0[4] += p1.x * v0; a1[4] += p1.x * v1v;
            a0[5] += p1.y * v0; a1[5] += p1.y * v1v;
            a0[6] += p1.z * v0; a1[6] += p1.z * v1v;
            a0[7] += p1.w * v0; a1[7] += p1.w * v1v;
        }
        #pragma unroll 8
        for (int u = 0; u < 8; u++) {
            if (u < nq) {
                fb[(qc + u) * 512 + tid] = a0[u];
                fb[(qc + u) * 512 + 256 + tid] = a1[u];
            }
        }
    }
}

// ============ attn2 MFMA: per (b,i,j) block, bf16 inputs, no input staging ============
__global__ __launch_bounds__(256) void attn2_mfma_kernel(
    const short* __restrict__ q2,
    const short* __restrict__ k2,
    const short* __restrict__ w2vT,
    const float* __restrict__ ep_b,
    float* __restrict__ fe_raw,     // (16,144,512)
    float* __restrict__ stats)      // (144,2)
{
    const int b = blockIdx.x, i = blockIdx.y, j = blockIdx.z;
    __shared__ float S[64 * 68];    // fp32 scores [q][key]
    __shared__ short P[64 * 88];    // bf16 probs  [q][key]
    __shared__ float red[256];
    const int tid = threadIdx.x;
    const int lane = tid & 63, w = tid >> 6;
    const int l15 = lane & 15, lk = lane >> 4;

    const short* qb = q2 + (size_t)((j * 16 + b) * 49) * 256;
    const short* kb = k2 + (size_t)((i * 16 + b) * 49) * 256;

    // ---- QK^T ----
    {
        int qrow = w * 16 + l15; if (qrow > 48) qrow = 48;
        f32x4 sacc[4] = {};
        #pragma unroll
        for (int ks = 0; ks < 8; ks++) {
            s16x8 aq = *reinterpret_cast<const s16x8*>(qb + (size_t)qrow * 256 + ks * 32 + lk * 8);
            #pragma unroll
            for (int ni = 0; ni < 4; ni++) {
                int krow = ni * 16 + l15; if (krow > 48) krow = 48;
                s16x8 bk = *reinterpret_cast<const s16x8*>(kb + (size_t)krow * 256 + ks * 32 + lk * 8);
                sacc[ni] = __builtin_amdgcn_mfma_f32_16x16x32_bf16(aq, bk, sacc[ni], 0, 0, 0);
            }
        }
        #pragma unroll
        for (int ni = 0; ni < 4; ni++)
            #pragma unroll
            for (int r = 0; r < 4; r++)
                S[(w * 16 + lk * 4 + r) * 68 + ni * 16 + l15] = sacc[ni][r] * 0.0625f;
    }
    __syncthreads();

    // ---- softmax; P bf16 with pads zeroed ----
    if (tid < 196) {
        int qi = tid >> 2, sub = tid & 3;
        float ev[13];
        float m = -1e30f;
        #pragma unroll 13
        for (int t = 0; t < 13; t++) {
            int kk = sub + t * 4;
            ev[t] = (kk < 49) ? S[qi * 68 + kk] : -1e30f;
            m = fmaxf(m, ev[t]);
        }
        m = fmaxf(m, __shfl_xor(m, 1));
        m = fmaxf(m, __shfl_xor(m, 2));
        float s = 0.f;
        #pragma unroll 13
        for (int t = 0; t < 13; t++) { ev[t] = __expf(ev[t] - m); s += ev[t]; }
        s += __shfl_xor(s, 1);
        s += __shfl_xor(s, 2);
        float inv = 1.f / s;
        #pragma unroll 13
        for (int t = 0; t < 13; t++) {
            int kk = sub + t * 4;
            if (kk < 49) P[qi * 88 + kk] = f2bf(ev[t] * inv);
        }
        for (int kk = 49 + sub; kk < 64; kk += 4) P[qi * 88 + kk] = 0;
    } else {
        int t2 = tid - 196;
        for (int idx = t2; idx < 15 * 64; idx += 60) {
            int rr = idx / 64, cc = idx - rr * 64;
            P[(49 + rr) * 88 + cc] = 0;
        }
    }
    __syncthreads();

    // ---- PV ----
    const short* vt = w2vT + (size_t)((i * 16 + b) * 512) * 64;
    const int slot = i * 12 + j;
    float tot = 0.f, csq = 0.f;
    #pragma unroll
    for (int half = 0; half < 2; half++) {
        const int cb = half * 256 + w * 64;
        f32x4 pac[4][4] = {};
        #pragma unroll
        for (int ks = 0; ks < 2; ks++) {
            s16x8 bv[4];
            #pragma unroll
            for (int ni = 0; ni < 4; ni++) {
                int ch = cb + ni * 16 + l15;
                bv[ni] = *reinterpret_cast<const s16x8*>(vt + (size_t)ch * 64 + ks * 32 + lk * 8);
            }
            #pragma unroll
            for (int mi = 0; mi < 4; mi++) {
                s16x8 ap = *reinterpret_cast<const s16x8*>(&P[(mi * 16 + l15) * 88 + ks * 32 + lk * 8]);
                #pragma unroll
                for (int ni = 0; ni < 4; ni++)
                    pac[mi][ni] = __builtin_amdgcn_mfma_f32_16x16x32_bf16(ap, bv[ni], pac[mi][ni], 0, 0, 0);
            }
        }
        #pragma unroll
        for (int ni = 0; ni < 4; ni++) {
            int col = cb + ni * 16 + l15;
            float bias = ep_b[col];
            float cs = 0.f;
            #pragma unroll
            for (int mi = 0; mi < 4; mi++) {
                #pragma unroll
                for (int r = 0; r < 4; r++) {
                    int row = mi * 16 + lk * 4 + r;
                    if (row < 49) {
                        float sv = pac[mi][ni][r] + bias;
                        cs += sv; csq += sv * sv;
                    }
                }
            }
            tot += cs;
            cs += __shfl_xor(cs, 16);
            cs += __shfl_xor(cs, 32);
            if (lk == 0)
                fe_raw[((size_t)b * 144 + slot) * 512 + col] = cs * (1.f / 49.f);
        }
    }
    red[tid] = tot; __syncthreads();
    for (int t = 128; t > 0; t >>= 1) { if (tid < t) red[tid] += red[tid + t]; __syncthreads(); }
    if (tid == 0) atomicAdd(&stats[slot * 2], red[0]);
    __syncthreads();
    red[tid] = csq; __syncthreads();
    for (int t = 128; t > 0; t >>= 1) { if (tid < t) red[tid] += red[tid + t]; __syncthreads(); }
    if (tid == 0) atomicAdd(&stats[slot * 2 + 1], red[0]);
}

// ============ finalize edge BN ============
__global__ __launch_bounds__(256) void edge_fin_kernel(
    const float* __restrict__ stats, float* __restrict__ fe)
{
    int s = blockIdx.x;
    const float inv = 1.f / 401408.f;
    float mu = stats[s * 2] * inv;
    float var = stats[s * 2 + 1] * inv - mu * mu;
    float rs = rsqrtf(var + BN_EPS);
    int tid = threadIdx.x;
    for (int b = 0; b < 16; b++) {
        float* p = fe + (b * 144 + s) * 512;
        #pragma unroll
        for (int half = 0; half < 2; half++) {
            int c = tid + half * 256;
            p[c] = (p[c] - mu) * rs;
        }
    }
}

// ============ GNN edge update ============
__global__ __launch_bounds__(256) void gnn_edge_kernel(
    const float* __restrict__ nodeproj,
    const float* __restrict__ eE,
    float* __restrict__ fe)
{
    int s = blockIdx.x;
    int i = s / 12, j = s - i * 12;
    int tid = threadIdx.x;
    const float* Vix = nodeproj + 2 * 98304;
    const float* Vjx = nodeproj + 3 * 98304;
    __shared__ float red[256];
    float msg[32];
    float sum = 0.f, sq = 0.f;
    int idx = 0;
    for (int b = 0; b < 16; b++) {
        #pragma unroll
        for (int half = 0; half < 2; half++) {
            int c = tid + half * 256;
            float v = Vjx[(b * 12 + i) * 512 + c] + Vix[(b * 12 + j) * 512 + c]
                    + eE[(b * 144 + s) * 512 + c];
            msg[idx++] = v;
            sum += v; sq += v * v;
        }
    }
    red[tid] = sum; __syncthreads();
    for (int t = 128; t > 0; t >>= 1) { if (tid < t) red[tid] += red[tid + t]; __syncthreads(); }
    float tsum = red[0]; __syncthreads();
    red[tid] = sq; __syncthreads();
    for (int t = 128; t > 0; t >>= 1) { if (tid < t) red[tid] += red[tid + t]; __syncthreads(); }
    float tsq = red[0];
    float mu = tsum * (1.f / 8192.f);
    float var = tsq * (1.f / 8192.f) - mu * mu;
    float rs = rsqrtf(var + BN_EPS);
    idx = 0;
    for (int b = 0; b < 16; b++) {
        #pragma unroll
        for (int half = 0; half < 2; half++) {
            int c = tid + half * 256;
            float v = fmaxf((msg[idx++] - mu) * rs, 0.f);
            fe[(b * 144 + s) * 512 + c] += v;
        }
    }
}

// ============ GNN aggregation ============
__global__ __launch_bounds__(256) void gnn_agg_kernel(
    const float* __restrict__ fe,
    const float* __restrict__ nodeproj,
    float* __restrict__ xn)
{
    int b = blockIdx.x;
    int tid = threadIdx.x;
    const float* Ux = nodeproj;
    const float* Ujx = nodeproj + 98304;
    #pragma unroll
    for (int half = 0; half < 2; half++) {
        int c = tid + half * 256;
        float agg[12];
        #pragma unroll
        for (int j = 0; j < 12; j++) agg[j] = 0.f;
        for (int i = 0; i < 12; i++) {
            float sg[12];
            float m = -1e30f;
            #pragma unroll
            for (int j = 0; j < 12; j++) {
                float e = fe[(b * 144 + i * 12 + j) * 512 + c];
                float sv = 1.f / (1.f + __expf(-e));
                sg[j] = sv;
                m = fmaxf(m, sv);
            }
            float ssum = 0.f;
            #pragma unroll
            for (int j = 0; j < 12; j++) { float evv = __expf(sg[j] - m); sg[j] = evv; ssum += evv; }
            float wgt = Ujx[(b * 12 + i) * 512 + c] / ssum;
            #pragma unroll
            for (int j = 0; j < 12; j++) agg[j] += sg[j] * wgt;
        }
        #pragma unroll
        for (int j = 0; j < 12; j++)
            xn[(b * 12 + j) * 512 + c] = Ux[(b * 12 + j) * 512 + c] + agg[j] * (1.f / 12.f);
    }
}

// ============ GNN node update ============
__global__ __launch_bounds__(256) void gnn_node_kernel(
    const float* __restrict__ xn, float* __restrict__ fv)
{
    int k = blockIdx.x;
    int tid = threadIdx.x;
    __shared__ float red[256];
    float vals[32];
    float sum = 0.f, sq = 0.f;
    int idx = 0;
    for (int b = 0; b < 16; b++) {
        #pragma unroll
        for (int half = 0; half < 2; half++) {
            int c = tid + half * 256;
            float v = xn[(b * 12 + k) * 512 + c];
            vals[idx++] = v;
            sum += v; sq += v * v;
        }
    }
    red[tid] = sum; __syncthreads();
    for (int t = 128; t > 0; t >>= 1) { if (tid < t) red[tid] += red[tid + t]; __syncthreads(); }
    float tsum = red[0]; __syncthreads();
    red[tid] = sq; __syncthreads();
    for (int t = 128; t > 0; t >>= 1) { if (tid < t) red[tid] += red[tid + t]; __syncthreads(); }
    float tsq = red[0];
    float mu = tsum * (1.f / 8192.f);
    float var = tsq * (1.f / 8192.f) - mu * mu;
    float rs = rsqrtf(var + BN_EPS);
    idx = 0;
    for (int b = 0; b < 16; b++) {
        #pragma unroll
        for (int half = 0; half < 2; half++) {
            int c = tid + half * 256;
            int o = (b * 12 + k) * 512 + c;
            float v = (vals[idx++] - mu) * rs;
            fv[o] = fmaxf(fv[o] + v, 0.f);
        }
    }
}

// ============ pairwise gather ============
__global__ __launch_bounds__(256) void pair_gather_kernel(
    const float* __restrict__ fe, const float* __restrict__ fv, float* __restrict__ pairX)
{
    int p = blockIdx.x;
    int b = blockIdx.y;
    int tid = threadIdx.x;
    int i = 0, rem = p;
    while (rem >= 11 - i) { rem -= 11 - i; i++; }
    int j = i + 1 + rem;
    float* e_out = pairX + (b * 66 + p) * 1024;
    float* n_out = pairX + 1056 * 1024 + (b * 66 + p) * 1024;
    const float* fe_ij = fe + (b * 144 + i * 12 + j) * 512;
    const float* fe_ji = fe + (b * 144 + j * 12 + i) * 512;
    const float* fv_i = fv + (b * 12 + i) * 512;
    const float* fv_j = fv + (b * 12 + j) * 512;
    #pragma unroll
    for (int half = 0; half < 2; half++) {
        int c = tid + half * 256;
        e_out[c] = fe_ij[c];
        e_out[512 + c] = fe_ji[c];
        n_out[c] = fv_i[c];
        n_out[512 + c] = fv_j[c];
    }
}

// ============ MLP layer 3 (Cout=4) ============
__global__ __launch_bounds__(256) void mlp3_kernel(
    const float* __restrict__ X,
    const float* __restrict__ w3,
    const float* __restrict__ b3,
    float* __restrict__ Y)
{
    int idx = blockIdx.x * 256 + threadIdx.x;
    if (idx >= 8448) return;
    int o = idx & 3;
    int r = (idx >> 2) % 1056;
    int m = idx / (4 * 1056);
    const float* x = X + (m * 1056 + r) * 256;
    const float* w = w3 + (m * 4 + o) * 256;
    float s = b3[m * 4 + o];
    #pragma unroll 8
    for (int c = 0; c < 256; c++) s += x[c] * w[c];
    Y[idx] = s;
}

// ============ final head ============
__global__ __launch_bounds__(256) void final_kernel(
    const float* __restrict__ mid3,
    const float* __restrict__ fw,
    const float* __restrict__ fb,
    float* __restrict__ out)
{
    int idx = blockIdx.x * 256 + threadIdx.x;
    if (idx >= 4224) return;
    int o = idx & 3;
    int r = idx >> 2;
    const float* ed = mid3 + r * 4;
    const float* nd = mid3 + 1056 * 4 + r * 4;
    float s = fb[o];
    #pragma unroll
    for (int q = 0; q < 4; q++) s += ed[q] * fw[o * 8 + q];
    #pragma unroll
    for (int q = 0; q < 4; q++) s += nd[q] * fw[o * 8 + 4 + q];
    out[idx] = s;
}

extern "C" void kernel_launch(void* const* d_in, const int* in_sizes, int n_in,
                              void* d_out, int out_size, void* d_ws, size_t ws_size,
                              hipStream_t stream)
{
    const float* x      = (const float*)d_in[0];
    const float* cls_w  = (const float*)d_in[1];
    const float* cls_b  = (const float*)d_in[2];
    const float* qw     = (const float*)d_in[3];
    const float* qb     = (const float*)d_in[4];
    const float* kw     = (const float*)d_in[5];
    const float* kb     = (const float*)d_in[6];
    const float* vw     = (const float*)d_in[7];
    const float* vb     = (const float*)d_in[8];
    const float* ep_w   = (const float*)d_in[9];
    const float* ep_b   = (const float*)d_in[10];
    const float* gnn_w  = (const float*)d_in[11];
    const float* mlp_w1 = (const float*)d_in[12];
    const float* mlp_b1 = (const float*)d_in[13];
    const float* mlp_w2 = (const float*)d_in[14];
    const float* mlp_b2 = (const float*)d_in[15];
    const float* mlp_w3 = (const float*)d_in[16];
    const float* mlp_b3 = (const float*)d_in[17];
    const float* fin_w  = (const float*)d_in[18];
    const float* fin_b  = (const float*)d_in[19];
    float* out = (float*)d_out;
    float* ws = (float*)d_ws;

    // ---- workspace layout (floats), ~75 MiB ----
    float* A     = ws;               // 4816896 : h/f_u ; later q2bf+k2bf (bf16)
    float* q1b   = A + 4816896;      // 2408448
    float* k1b   = q1b + 2408448;    // 200704
    float* v1b   = k1b + 200704;     // 401408
    float* Bb    = v1b + 401408;     // 4816896 : feat ; later w2vT (bf16)
    float* Cb    = Bb + 4816896;     // 4816896 : v2 -> gnn temps -> pair temps
    float* fv    = Cb + 4816896;     // 98304
    float* bn1m  = fv + 98304;       // 6144 : Σ per (k,o)
    float* bn1r  = bn1m + 6144;      // 6144 : Σ² per (k,o)
    float* fe    = bn1r + 6144;      // 1179648
    float* stats = fe + 1179648;     // 288

    short* q2bf = (short*)A;                    // (12,16,49,256) bf16
    short* k2bf = (short*)(A + 1204224);        // (12,16,49,256) bf16
    float* v2b  = Cb;                           // (12,16,49,512) fp32
    short* w2vT = (short*)Bb;                   // (12,16,512,64) bf16

    // GNN temps in Cb (after v2 dead)
    float* nodeproj = Cb;            // [4][16][12][512]
    float* eE       = Cb + 393216;
    float* xn       = Cb + 1572864;
    // pair temps in Cb (GNN temps dead)
    float* pairX = Cb;
    float* mid1  = Cb + 2162688;
    float* mid2  = Cb + 3244032;
    float* mid3  = Cb + 3784704;

    // 1. h = x @ cls_w^T + cls_b  (per class)
    mfma_linear_kernel<0><<<dim3(8, 13, 12), 256, 0, stream>>>(x, 0, cls_w, 262144, cls_b, 512,
                                                               A, 401408, 784, 512, 512, 0);
    // 2-3. BN1 stats: parallel partials (12x8 blocks) + fused mu/rstd in fu_fv
    hipMemsetAsync(bn1m, 0, 2 * 6144 * sizeof(float), stream);
    bn1_partial_kernel<<<dim3(12, 8), 256, 0, stream>>>(A, bn1m, bn1r);
    fu_fv_kernel<<<dim3(16, 12), 256, 0, stream>>>(A, bn1m, bn1r, fv);
    // 4. q1 = f_u @ qw0^T + qb0
    mfma_linear_kernel<0><<<dim3(4, 147, 1), 256, 0, stream>>>(A, 0, qw, 0, qb, 0,
                                                               q1b, 0, 9408, 512, 256, 0);
    // 5-6. k1/v1 from x
    mfma_linear_kernel<0><<<dim3(4, 13, 1), 256, 0, stream>>>(x, 0, kw, 0, kb, 0,
                                                              k1b, 0, 784, 512, 256, 0);
    mfma_linear_kernel<0><<<dim3(8, 13, 1), 256, 0, stream>>>(x, 0, vw, 0, vb, 0,
                                                              v1b, 0, 784, 512, 512, 0);
    // 7. feat = attn1
    attn1_kernel<<<dim3(16, 12), 256, 0, stream>>>(q1b, k1b, v1b, Bb);
    // 8-10. q2/k2 (bf16 out), v2 (fp32) from feat
    mfma_linear_kernel<1><<<dim3(4, 147, 1), 256, 0, stream>>>(Bb, 0, qw + 131072, 0, qb + 256, 0,
                                                               q2bf, 0, 9408, 512, 256, 0);
    mfma_linear_kernel<1><<<dim3(4, 147, 1), 256, 0, stream>>>(Bb, 0, kw + 131072, 0, kb + 256, 0,
                                                               k2bf, 0, 9408, 512, 256, 0);
    mfma_linear_kernel<0><<<dim3(8, 147, 1), 256, 0, stream>>>(Bb, 0, vw + 262144, 0, vb + 512, 0,
                                                               v2b, 0, 9408, 512, 512, 0);
    // 11. w2vT = (v2 @ ep_w^T) transposed per-tile, bf16. Pre-zero so pad keys are 0.
    hipMemsetAsync(w2vT, 0, (size_t)12 * 16 * 512 * 64 * sizeof(short), stream);
    mfma_linear_kernel<2><<<dim3(8, 147, 1), 256, 0, stream>>>(v2b, 0, ep_w, 0, nullptr, 0,
                                                               w2vT, 0, 9408, 512, 512, 0);
    // 12-14. MFMA attn2 + edge BN
    hipMemsetAsync(stats, 0, 288 * sizeof(float), stream);
    attn2_mfma_kernel<<<dim3(16, 12, 12), 256, 0, stream>>>(q2bf, k2bf, w2vT, ep_b, fe, stats);
    edge_fin_kernel<<<144, 256, 0, stream>>>(stats, fe);

    // 15-16. two GCN blocks
    for (int blk = 0; blk < 2; blk++) {
        const float* gw = gnn_w + blk * 5 * 262144;  // U,V,A,B,E
        mfma_linear_kernel<0><<<dim3(8, 3, 4), 256, 0, stream>>>(fv, 0, gw, 262144, nullptr, 0,
                                                                 nodeproj, 98304, 192, 512, 512, 0);
        mfma_linear_kernel<0><<<dim3(8, 36, 1), 256, 0, stream>>>(fe, 0, gw + 4 * 262144, 0, nullptr, 0,
                                                                  eE, 0, 2304, 512, 512, 0);
        gnn_edge_kernel<<<144, 256, 0, stream>>>(nodeproj, eE, fe);
        gnn_agg_kernel<<<16, 256, 0, stream>>>(fe, nodeproj, xn);
        gnn_node_kernel<<<12, 256, 0, stream>>>(xn, fv);
    }

    // 17. pairwise gather
    pair_gather_kernel<<<dim3(66, 16), 256, 0, stream>>>(fe, fv, pairX);
    // 18-19. MLP layers 1-2
    mfma_linear_kernel<0><<<dim3(8, 17, 2), 256, 0, stream>>>(pairX, 1081344, mlp_w1, 524288, mlp_b1, 512,
                                                              mid1, 540672, 1056, 1024, 512, 1);
    mfma_linear_kernel<0><<<dim3(4, 17, 2), 256, 0, stream>>>(mid1, 540672, mlp_w2, 131072, mlp_b2, 256,
                                                              mid2, 270336, 1056, 512, 256, 1);
    // 20. MLP layer 3
    mlp3_kernel<<<33, 256, 0, stream>>>(mid2, mlp_w3, mlp_b3, mid3);
    // 21. final head
    final_kernel<<<17, 256, 0, stream>>>(mid3, fin_w, fin_b, out);
}

// Round 8
// 508.635 us; speedup vs baseline: 6.1444x; 1.3336x over previous
//
#include <hip/hip_runtime.h>

#define BN_EPS 1e-5f

typedef float f32x4 __attribute__((ext_vector_type(4)));
typedef short s16x8 __attribute__((ext_vector_type(8)));

__device__ __forceinline__ short f2bf(float f) {
    unsigned u = __builtin_bit_cast(unsigned, f);
    u = (u + 0x7fffu + ((u >> 16) & 1u)) >> 16;   // RNE
    return (short)u;
}

// ============ MFMA bf16 linear: Y = act(X @ W^T + b), fp32 in ============
// OMODE 0: fp32 out row-major. 1: bf16 out row-major. 2: bf16 out, transposed
// per-49-row tile -> [tile][Cout=512][64] (keys padded to 64; pad pre-zeroed by host memset).
template<int OMODE>
__global__ __launch_bounds__(256) void mfma_linear_kernel(
    const float* __restrict__ X, int Xstride,
    const float* __restrict__ W, int Wstride,
    const float* __restrict__ bias, int bstride,
    void* __restrict__ Yv, int Ystride,
    int R, int Cin, int Cout, int relu)
{
    const int mat = blockIdx.z;
    X += (size_t)mat * Xstride;
    W += (size_t)mat * Wstride;
    const float* bp = bias ? bias + mat * bstride : nullptr;
    float* Yf = (float*)Yv + (size_t)mat * Ystride;
    short* Ys = (short*)Yv + (size_t)mat * Ystride;

    const int r0 = blockIdx.y * 64;
    const int o0 = blockIdx.x * 64;

    __shared__ short As[64 * 40];   // 80B row stride: 20 banks, 2-way alias = free
    __shared__ short Bs[64 * 40];

    const int tid = threadIdx.x;
    const int lane = tid & 63;
    const int wave = tid >> 6;
    const int wr = wave >> 1, wc = wave & 1;
    const int l15 = lane & 15;
    const int lk = lane >> 4;

    const int trow = tid >> 2;
    const int tseg = (tid & 3) * 8;

    f32x4 acc[2][2] = {};

    const int arow = r0 + trow;
    const bool aok = arow < R;
    const float* xrow = X + (size_t)arow * Cin + tseg;
    const float* wrow = W + (size_t)(o0 + trow) * Cin + tseg;

    for (int k0 = 0; k0 < Cin; k0 += 32) {
        float4 a0 = {}, a1 = {};
        if (aok) {
            a0 = *reinterpret_cast<const float4*>(xrow + k0);
            a1 = *reinterpret_cast<const float4*>(xrow + k0 + 4);
        }
        float4 b0 = *reinterpret_cast<const float4*>(wrow + k0);
        float4 b1 = *reinterpret_cast<const float4*>(wrow + k0 + 4);
        s16x8 av, bv;
        av[0] = f2bf(a0.x); av[1] = f2bf(a0.y); av[2] = f2bf(a0.z); av[3] = f2bf(a0.w);
        av[4] = f2bf(a1.x); av[5] = f2bf(a1.y); av[6] = f2bf(a1.z); av[7] = f2bf(a1.w);
        bv[0] = f2bf(b0.x); bv[1] = f2bf(b0.y); bv[2] = f2bf(b0.z); bv[3] = f2bf(b0.w);
        bv[4] = f2bf(b1.x); bv[5] = f2bf(b1.y); bv[6] = f2bf(b1.z); bv[7] = f2bf(b1.w);
        *reinterpret_cast<s16x8*>(&As[trow * 40 + tseg]) = av;
        *reinterpret_cast<s16x8*>(&Bs[trow * 40 + tseg]) = bv;
        __syncthreads();

        s16x8 af[2], bf[2];
        #pragma unroll
        for (int mi = 0; mi < 2; mi++)
            af[mi] = *reinterpret_cast<const s16x8*>(&As[(wr * 32 + mi * 16 + l15) * 40 + lk * 8]);
        #pragma unroll
        for (int ni = 0; ni < 2; ni++)
            bf[ni] = *reinterpret_cast<const s16x8*>(&Bs[(wc * 32 + ni * 16 + l15) * 40 + lk * 8]);
        #pragma unroll
        for (int mi = 0; mi < 2; mi++)
            #pragma unroll
            for (int ni = 0; ni < 2; ni++)
                acc[mi][ni] = __builtin_amdgcn_mfma_f32_16x16x32_bf16(af[mi], bf[ni], acc[mi][ni], 0, 0, 0);
        __syncthreads();
    }

    #pragma unroll
    for (int mi = 0; mi < 2; mi++) {
        #pragma unroll
        for (int ni = 0; ni < 2; ni++) {
            int col = o0 + wc * 32 + ni * 16 + l15;
            int row0 = r0 + wr * 32 + mi * 16 + lk * 4;
            float bb = bp ? bp[col] : 0.f;
            #pragma unroll
            for (int r = 0; r < 4; r++) {
                int row = row0 + r;
                if (row < R) {
                    float v = acc[mi][ni][r] + bb;
                    if (relu) v = fmaxf(v, 0.f);
                    if (OMODE == 0) {
                        Yf[(size_t)row * Cout + col] = v;
                    } else if (OMODE == 1) {
                        Ys[(size_t)row * Cout + col] = f2bf(v);
                    } else {
                        int t = row / 49, n = row - t * 49;
                        Ys[((size_t)t * 512 + col) * 64 + n] = f2bf(v);
                    }
                }
            }
        }
    }
}

// ============ BN1 partial stats: grid (12, 8); atomicAdd (sum, sumsq) per (k,o) ============
__global__ __launch_bounds__(256) void bn1_partial_kernel(
    const float* __restrict__ h, float* __restrict__ bsum, float* __restrict__ bsq)
{
    int k = blockIdx.x;          // class
    int part = blockIdx.y;       // 0..7, rows [part*98, +98)
    int tid = threadIdx.x;
    #pragma unroll
    for (int half = 0; half < 2; half++) {
        int o = tid + half * 256;
        const float* base = h + (size_t)k * 401408 + (size_t)part * 98 * 512 + o;
        float s = 0.f, sq = 0.f;
        #pragma unroll 7
        for (int bn = 0; bn < 98; bn++) {
            float v = base[bn * 512];
            s += v; sq += v * v;
        }
        atomicAdd(&bsum[k * 512 + o], s);
        atomicAdd(&bsq[k * 512 + o], sq);
    }
}

// ============ f_u = relu(bn(h)) in place; f_v = mean_n f_u. mu/rstd from (sum,sq) ============
__global__ __launch_bounds__(256) void fu_fv_kernel(
    float* __restrict__ h, const float* __restrict__ bsum,
    const float* __restrict__ bsq, float* __restrict__ f_v)
{
    int b = blockIdx.x;
    int k = blockIdx.y;
    int tid = threadIdx.x;
    #pragma unroll
    for (int half = 0; half < 2; half++) {
        int o = tid + half * 256;
        float mu = bsum[k * 512 + o] * (1.f / 784.f);
        float var = bsq[k * 512 + o] * (1.f / 784.f) - mu * mu;
        float rs = rsqrtf(var + BN_EPS);
        float* base = h + (size_t)(k * 16 + b) * 49 * 512 + o;
        float acc = 0.f;
        #pragma unroll 7
        for (int n = 0; n < 49; n++) {
            float v = (base[n * 512] - mu) * rs;
            v = fmaxf(v, 0.f);
            base[n * 512] = v;
            acc += v;
        }
        f_v[(b * 12 + k) * 512 + o] = acc * (1.f / 49.f);
    }
}

// ============ attn1 (fp32 VALU; tile L2-resident) ============
__global__ __launch_bounds__(256) void attn1_kernel(
    const float* __restrict__ q1,  // (12,16,49,256)
    const float* __restrict__ k1,  // (16,49,256)
    const float* __restrict__ v1,  // (16,49,512)
    float* __restrict__ feat)      // (12,16,49,512)
{
    int b = blockIdx.x;
    int k = blockIdx.y;
    __shared__ float ks[49 * 260];
    __shared__ float Pt[49 * 56];
    int tid = threadIdx.x;
    const float* kb = k1 + b * 49 * 256;
    for (int e = tid; e < 49 * 256; e += 256) ks[(e >> 8) * 260 + (e & 255)] = kb[e];
    __syncthreads();
    const float* qb = q1 + (k * 16 + b) * 49 * 256;
    for (int e = tid; e < 49 * 49; e += 256) {
        int qi = e / 49, kj = e - qi * 49;
        const float4* q4 = reinterpret_cast<const float4*>(qb + qi * 256);
        const float4* k4 = reinterpret_cast<const float4*>(ks + kj * 260);
        float s = 0.f;
        #pragma unroll 8
        for (int d = 0; d < 64; d++) {
            float4 a = q4[d], c = k4[d];
            s += a.x * c.x + a.y * c.y + a.z * c.z + a.w * c.w;
        }
        Pt[kj * 56 + qi] = s * 0.0625f;
    }
    __syncthreads();
    if (tid < 196) {
        int qi = tid >> 2, sub = tid & 3;
        float ev[13];
        float m = -1e30f;
        #pragma unroll 13
        for (int t = 0; t < 13; t++) {
            int j = sub + t * 4;
            ev[t] = (j < 49) ? Pt[j * 56 + qi] : -1e30f;
            m = fmaxf(m, ev[t]);
        }
        m = fmaxf(m, __shfl_xor(m, 1));
        m = fmaxf(m, __shfl_xor(m, 2));
        float s = 0.f;
        #pragma unroll 13
        for (int t = 0; t < 13; t++) { ev[t] = __expf(ev[t] - m); s += ev[t]; }
        s += __shfl_xor(s, 1);
        s += __shfl_xor(s, 2);
        float inv = 1.f / s;
        #pragma unroll 13
        for (int t = 0; t < 13; t++) {
            int j = sub + t * 4;
            if (j < 49) Pt[j * 56 + qi] = ev[t] * inv;
        }
    }
    __syncthreads();
    const float* vb = v1 + b * 49 * 512;
    float* fb = feat + (k * 16 + b) * 49 * 512;
    for (int qc = 0; qc < 49; qc += 8) {
        int nq = 49 - qc; if (nq > 8) nq = 8;
        float a0[8] = {}, a1[8] = {};
        for (int kj = 0; kj < 49; kj++) {
            float v0 = vb[kj * 512 + tid];
            float v1v = vb[kj * 512 + 256 + tid];
            const float4* pr = reinterpret_cast<const float4*>(&Pt[kj * 56 + qc]);
            float4 p0 = pr[0], p1 = pr[1];
            a0[0] += p0.x * v0; a1[0] += p0.x * v1v;
            a0[1] += p0.y * v0; a1[1] += p0.y * v1v;
            a0[2] += p0.z * v0; a1[2] += p0.z * v1v;
            a0[3] += p0.w * v0; a1[3] += p0.w * v1v;
            a0[4] += p1.x * v0; a1[4] += p1.x * v1v;
            a0[5] += p1.y * v0; a1[5] += p1.y * v1v;
            a0[6] += p1.z * v0; a1[6] += p1.z * v1v;
            a0[7] += p1.w * v0; a1[7] += p1.w * v1v;
        }
        #pragma unroll 8
        for (int u = 0; u < 8; u++) {
            if (u < nq) {
                fb[(qc + u) * 512 + tid] = a0[u];
                fb[(qc + u) * 512 + 256 + tid] = a1[u];
            }
        }
    }
}

// ============ attn2 MFMA: per (b,i,j) block, bf16 inputs, no input staging ============
__global__ __launch_bounds__(256) void attn2_mfma_kernel(
    const short* __restrict__ q2,
    const short* __restrict__ k2,
    const short* __restrict__ w2vT,
    const float* __restrict__ ep_b,
    float* __restrict__ fe_raw,     // (16,144,512)
    float* __restrict__ stats)      // (144,2)
{
    const int b = blockIdx.x, i = blockIdx.y, j = blockIdx.z;
    __shared__ float S[64 * 68];    // fp32 scores [q][key]
    __shared__ short P[64 * 88];    // bf16 probs  [q][key]
    __shared__ float red[256];
    const int tid = threadIdx.x;
    const int lane = tid & 63, w = tid >> 6;
    const int l15 = lane & 15, lk = lane >> 4;

    const short* qb = q2 + (size_t)((j * 16 + b) * 49) * 256;
    const short* kb = k2 + (size_t)((i * 16 + b) * 49) * 256;

    // ---- QK^T ----
    {
        int qrow = w * 16 + l15; if (qrow > 48) qrow = 48;
        f32x4 sacc[4] = {};
        #pragma unroll
        for (int ks = 0; ks < 8; ks++) {
            s16x8 aq = *reinterpret_cast<const s16x8*>(qb + (size_t)qrow * 256 + ks * 32 + lk * 8);
            #pragma unroll
            for (int ni = 0; ni < 4; ni++) {
                int krow = ni * 16 + l15; if (krow > 48) krow = 48;
                s16x8 bk = *reinterpret_cast<const s16x8*>(kb + (size_t)krow * 256 + ks * 32 + lk * 8);
                sacc[ni] = __builtin_amdgcn_mfma_f32_16x16x32_bf16(aq, bk, sacc[ni], 0, 0, 0);
            }
        }
        #pragma unroll
        for (int ni = 0; ni < 4; ni++)
            #pragma unroll
            for (int r = 0; r < 4; r++)
                S[(w * 16 + lk * 4 + r) * 68 + ni * 16 + l15] = sacc[ni][r] * 0.0625f;
    }
    __syncthreads();

    // ---- softmax; P bf16 with pads zeroed ----
    if (tid < 196) {
        int qi = tid >> 2, sub = tid & 3;
        float ev[13];
        float m = -1e30f;
        #pragma unroll 13
        for (int t = 0; t < 13; t++) {
            int kk = sub + t * 4;
            ev[t] = (kk < 49) ? S[qi * 68 + kk] : -1e30f;
            m = fmaxf(m, ev[t]);
        }
        m = fmaxf(m, __shfl_xor(m, 1));
        m = fmaxf(m, __shfl_xor(m, 2));
        float s = 0.f;
        #pragma unroll 13
        for (int t = 0; t < 13; t++) { ev[t] = __expf(ev[t] - m); s += ev[t]; }
        s += __shfl_xor(s, 1);
        s += __shfl_xor(s, 2);
        float inv = 1.f / s;
        #pragma unroll 13
        for (int t = 0; t < 13; t++) {
            int kk = sub + t * 4;
            if (kk < 49) P[qi * 88 + kk] = f2bf(ev[t] * inv);
        }
        for (int kk = 49 + sub; kk < 64; kk += 4) P[qi * 88 + kk] = 0;
    } else {
        int t2 = tid - 196;
        for (int idx = t2; idx < 15 * 64; idx += 60) {
            int rr = idx / 64, cc = idx - rr * 64;
            P[(49 + rr) * 88 + cc] = 0;
        }
    }
    __syncthreads();

    // ---- PV ----
    const short* vt = w2vT + (size_t)((i * 16 + b) * 512) * 64;
    const int slot = i * 12 + j;
    float tot = 0.f, csq = 0.f;
    #pragma unroll
    for (int half = 0; half < 2; half++) {
        const int cb = half * 256 + w * 64;
        f32x4 pac[4][4] = {};
        #pragma unroll
        for (int ks = 0; ks < 2; ks++) {
            s16x8 bv[4];
            #pragma unroll
            for (int ni = 0; ni < 4; ni++) {
                int ch = cb + ni * 16 + l15;
                bv[ni] = *reinterpret_cast<const s16x8*>(vt + (size_t)ch * 64 + ks * 32 + lk * 8);
            }
            #pragma unroll
            for (int mi = 0; mi < 4; mi++) {
                s16x8 ap = *reinterpret_cast<const s16x8*>(&P[(mi * 16 + l15) * 88 + ks * 32 + lk * 8]);
                #pragma unroll
                for (int ni = 0; ni < 4; ni++)
                    pac[mi][ni] = __builtin_amdgcn_mfma_f32_16x16x32_bf16(ap, bv[ni], pac[mi][ni], 0, 0, 0);
            }
        }
        #pragma unroll
        for (int ni = 0; ni < 4; ni++) {
            int col = cb + ni * 16 + l15;
            float bias = ep_b[col];
            float cs = 0.f;
            #pragma unroll
            for (int mi = 0; mi < 4; mi++) {
                #pragma unroll
                for (int r = 0; r < 4; r++) {
                    int row = mi * 16 + lk * 4 + r;
                    if (row < 49) {
                        float sv = pac[mi][ni][r] + bias;
                        cs += sv; csq += sv * sv;
                    }
                }
            }
            tot += cs;
            cs += __shfl_xor(cs, 16);
            cs += __shfl_xor(cs, 32);
            if (lk == 0)
                fe_raw[((size_t)b * 144 + slot) * 512 + col] = cs * (1.f / 49.f);
        }
    }
    red[tid] = tot; __syncthreads();
    for (int t = 128; t > 0; t >>= 1) { if (tid < t) red[tid] += red[tid + t]; __syncthreads(); }
    if (tid == 0) atomicAdd(&stats[slot * 2], red[0]);
    __syncthreads();
    red[tid] = csq; __syncthreads();
    for (int t = 128; t > 0; t >>= 1) { if (tid < t) red[tid] += red[tid + t]; __syncthreads(); }
    if (tid == 0) atomicAdd(&stats[slot * 2 + 1], red[0]);
}

// ============ finalize edge BN ============
__global__ __launch_bounds__(256) void edge_fin_kernel(
    const float* __restrict__ stats, float* __restrict__ fe)
{
    int s = blockIdx.x;
    const float inv = 1.f / 401408.f;
    float mu = stats[s * 2] * inv;
    float var = stats[s * 2 + 1] * inv - mu * mu;
    float rs = rsqrtf(var + BN_EPS);
    int tid = threadIdx.x;
    for (int b = 0; b < 16; b++) {
        float* p = fe + (b * 144 + s) * 512;
        #pragma unroll
        for (int half = 0; half < 2; half++) {
            int c = tid + half * 256;
            p[c] = (p[c] - mu) * rs;
        }
    }
}

// ============ GNN edge update ============
__global__ __launch_bounds__(256) void gnn_edge_kernel(
    const float* __restrict__ nodeproj,
    const float* __restrict__ eE,
    float* __restrict__ fe)
{
    int s = blockIdx.x;
    int i = s / 12, j = s - i * 12;
    int tid = threadIdx.x;
    const float* Vix = nodeproj + 2 * 98304;
    const float* Vjx = nodeproj + 3 * 98304;
    __shared__ float red[256];
    float msg[32];
    float sum = 0.f, sq = 0.f;
    int idx = 0;
    for (int b = 0; b < 16; b++) {
        #pragma unroll
        for (int half = 0; half < 2; half++) {
            int c = tid + half * 256;
            float v = Vjx[(b * 12 + i) * 512 + c] + Vix[(b * 12 + j) * 512 + c]
                    + eE[(b * 144 + s) * 512 + c];
            msg[idx++] = v;
            sum += v; sq += v * v;
        }
    }
    red[tid] = sum; __syncthreads();
    for (int t = 128; t > 0; t >>= 1) { if (tid < t) red[tid] += red[tid + t]; __syncthreads(); }
    float tsum = red[0]; __syncthreads();
    red[tid] = sq; __syncthreads();
    for (int t = 128; t > 0; t >>= 1) { if (tid < t) red[tid] += red[tid + t]; __syncthreads(); }
    float tsq = red[0];
    float mu = tsum * (1.f / 8192.f);
    float var = tsq * (1.f / 8192.f) - mu * mu;
    float rs = rsqrtf(var + BN_EPS);
    idx = 0;
    for (int b = 0; b < 16; b++) {
        #pragma unroll
        for (int half = 0; half < 2; half++) {
            int c = tid + half * 256;
            float v = fmaxf((msg[idx++] - mu) * rs, 0.f);
            fe[(b * 144 + s) * 512 + c] += v;
        }
    }
}

// ============ GNN aggregation: grid (16,12) over (b, source i); atomicAdd into xn_agg ============
__global__ __launch_bounds__(256) void gnn_agg_kernel(
    const float* __restrict__ fe,        // updated edges (16,144,512)
    const float* __restrict__ nodeproj,  // 1=Ujx at +98304
    float* __restrict__ xn_agg)          // (16,12,512), pre-zeroed; accumulates Σ_i sg*w
{
    int b = blockIdx.x;
    int i = blockIdx.y;
    int tid = threadIdx.x;
    const float* Ujx = nodeproj + 98304;
    #pragma unroll
    for (int half = 0; half < 2; half++) {
        int c = tid + half * 256;
        float sg[12];
        float m = -1e30f;
        #pragma unroll
        for (int j = 0; j < 12; j++) {
            float e = fe[(b * 144 + i * 12 + j) * 512 + c];
            float sv = 1.f / (1.f + __expf(-e));
            sg[j] = sv;
            m = fmaxf(m, sv);
        }
        float ssum = 0.f;
        #pragma unroll
        for (int j = 0; j < 12; j++) { float evv = __expf(sg[j] - m); sg[j] = evv; ssum += evv; }
        float wgt = Ujx[(b * 12 + i) * 512 + c] / ssum;
        #pragma unroll
        for (int j = 0; j < 12; j++)
            atomicAdd(&xn_agg[(b * 12 + j) * 512 + c], sg[j] * wgt);
    }
}

// ============ GNN node update: val = Ux + xn_agg/12 ; fv = relu(fv + bn_class(val)) ============
__global__ __launch_bounds__(256) void gnn_node_kernel(
    const float* __restrict__ xn_agg, const float* __restrict__ nodeproj,
    float* __restrict__ fv)
{
    int k = blockIdx.x;
    int tid = threadIdx.x;
    const float* Ux = nodeproj;
    __shared__ float red[256];
    float vals[32];
    float sum = 0.f, sq = 0.f;
    int idx = 0;
    for (int b = 0; b < 16; b++) {
        #pragma unroll
        for (int half = 0; half < 2; half++) {
            int c = tid + half * 256;
            int o = (b * 12 + k) * 512 + c;
            float v = Ux[o] + xn_agg[o] * (1.f / 12.f);
            vals[idx++] = v;
            sum += v; sq += v * v;
        }
    }
    red[tid] = sum; __syncthreads();
    for (int t = 128; t > 0; t >>= 1) { if (tid < t) red[tid] += red[tid + t]; __syncthreads(); }
    float tsum = red[0]; __syncthreads();
    red[tid] = sq; __syncthreads();
    for (int t = 128; t > 0; t >>= 1) { if (tid < t) red[tid] += red[tid + t]; __syncthreads(); }
    float tsq = red[0];
    float mu = tsum * (1.f / 8192.f);
    float var = tsq * (1.f / 8192.f) - mu * mu;
    float rs = rsqrtf(var + BN_EPS);
    idx = 0;
    for (int b = 0; b < 16; b++) {
        #pragma unroll
        for (int half = 0; half < 2; half++) {
            int c = tid + half * 256;
            int o = (b * 12 + k) * 512 + c;
            float v = (vals[idx++] - mu) * rs;
            fv[o] = fmaxf(fv[o] + v, 0.f);
        }
    }
}

// ============ pairwise gather ============
__global__ __launch_bounds__(256) void pair_gather_kernel(
    const float* __restrict__ fe, const float* __restrict__ fv, float* __restrict__ pairX)
{
    int p = blockIdx.x;
    int b = blockIdx.y;
    int tid = threadIdx.x;
    int i = 0, rem = p;
    while (rem >= 11 - i) { rem -= 11 - i; i++; }
    int j = i + 1 + rem;
    float* e_out = pairX + (b * 66 + p) * 1024;
    float* n_out = pairX + 1056 * 1024 + (b * 66 + p) * 1024;
    const float* fe_ij = fe + (b * 144 + i * 12 + j) * 512;
    const float* fe_ji = fe + (b * 144 + j * 12 + i) * 512;
    const float* fv_i = fv + (b * 12 + i) * 512;
    const float* fv_j = fv + (b * 12 + j) * 512;
    #pragma unroll
    for (int half = 0; half < 2; half++) {
        int c = tid + half * 256;
        e_out[c] = fe_ij[c];
        e_out[512 + c] = fe_ji[c];
        n_out[c] = fv_i[c];
        n_out[512 + c] = fv_j[c];
    }
}

// ============ MLP layer 3 (Cout=4) ============
__global__ __launch_bounds__(256) void mlp3_kernel(
    const float* __restrict__ X,
    const float* __restrict__ w3,
    const float* __restrict__ b3,
    float* __restrict__ Y)
{
    int idx = blockIdx.x * 256 + threadIdx.x;
    if (idx >= 8448) return;
    int o = idx & 3;
    int r = (idx >> 2) % 1056;
    int m = idx / (4 * 1056);
    const float* x = X + (m * 1056 + r) * 256;
    const float* w = w3 + (m * 4 + o) * 256;
    float s = b3[m * 4 + o];
    #pragma unroll 8
    for (int c = 0; c < 256; c++) s += x[c] * w[c];
    Y[idx] = s;
}

// ============ final head ============
__global__ __launch_bounds__(256) void final_kernel(
    const float* __restrict__ mid3,
    const float* __restrict__ fw,
    const float* __restrict__ fb,
    float* __restrict__ out)
{
    int idx = blockIdx.x * 256 + threadIdx.x;
    if (idx >= 4224) return;
    int o = idx & 3;
    int r = idx >> 2;
    const float* ed = mid3 + r * 4;
    const float* nd = mid3 + 1056 * 4 + r * 4;
    float s = fb[o];
    #pragma unroll
    for (int q = 0; q < 4; q++) s += ed[q] * fw[o * 8 + q];
    #pragma unroll
    for (int q = 0; q < 4; q++) s += nd[q] * fw[o * 8 + 4 + q];
    out[idx] = s;
}

extern "C" void kernel_launch(void* const* d_in, const int* in_sizes, int n_in,
                              void* d_out, int out_size, void* d_ws, size_t ws_size,
                              hipStream_t stream)
{
    const float* x      = (const float*)d_in[0];
    const float* cls_w  = (const float*)d_in[1];
    const float* cls_b  = (const float*)d_in[2];
    const float* qw     = (const float*)d_in[3];
    const float* qb     = (const float*)d_in[4];
    const float* kw     = (const float*)d_in[5];
    const float* kb     = (const float*)d_in[6];
    const float* vw     = (const float*)d_in[7];
    const float* vb     = (const float*)d_in[8];
    const float* ep_w   = (const float*)d_in[9];
    const float* ep_b   = (const float*)d_in[10];
    const float* gnn_w  = (const float*)d_in[11];
    const float* mlp_w1 = (const float*)d_in[12];
    const float* mlp_b1 = (const float*)d_in[13];
    const float* mlp_w2 = (const float*)d_in[14];
    const float* mlp_b2 = (const float*)d_in[15];
    const float* mlp_w3 = (const float*)d_in[16];
    const float* mlp_b3 = (const float*)d_in[17];
    const float* fin_w  = (const float*)d_in[18];
    const float* fin_b  = (const float*)d_in[19];
    float* out = (float*)d_out;
    float* ws = (float*)d_ws;

    // ---- workspace layout (floats), ~75 MiB ----
    float* A     = ws;               // 4816896 : h/f_u ; later q2bf+k2bf (bf16)
    float* q1b   = A + 4816896;      // 2408448
    float* k1b   = q1b + 2408448;    // 200704
    float* v1b   = k1b + 200704;     // 401408
    float* Bb    = v1b + 401408;     // 4816896 : feat ; later w2vT (bf16)
    float* Cb    = Bb + 4816896;     // 4816896 : v2 -> gnn temps -> pair temps
    float* fv    = Cb + 4816896;     // 98304
    float* bn1m  = fv + 98304;       // 6144 : Σ per (k,o)
    float* bn1r  = bn1m + 6144;      // 6144 : Σ² per (k,o)
    float* fe    = bn1r + 6144;      // 1179648
    float* stats = fe + 1179648;     // 288

    short* q2bf = (short*)A;                    // (12,16,49,256) bf16
    short* k2bf = (short*)(A + 1204224);        // (12,16,49,256) bf16
    float* v2b  = Cb;                           // (12,16,49,512) fp32
    short* w2vT = (short*)Bb;                   // (12,16,512,64) bf16

    // GNN temps in Cb (after v2 dead)
    float* nodeproj = Cb;            // [4][16][12][512]
    float* eE       = Cb + 393216;
    float* xn       = Cb + 1572864;  // agg accumulator (16,12,512)
    // pair temps in Cb (GNN temps dead)
    float* pairX = Cb;
    float* mid1  = Cb + 2162688;
    float* mid2  = Cb + 3244032;
    float* mid3  = Cb + 3784704;

    // 1. h = x @ cls_w^T + cls_b  (per class)
    mfma_linear_kernel<0><<<dim3(8, 13, 12), 256, 0, stream>>>(x, 0, cls_w, 262144, cls_b, 512,
                                                               A, 401408, 784, 512, 512, 0);
    // 2-3. BN1 stats: parallel partials (12x8 blocks) + fused mu/rstd in fu_fv
    hipMemsetAsync(bn1m, 0, 2 * 6144 * sizeof(float), stream);
    bn1_partial_kernel<<<dim3(12, 8), 256, 0, stream>>>(A, bn1m, bn1r);
    fu_fv_kernel<<<dim3(16, 12), 256, 0, stream>>>(A, bn1m, bn1r, fv);
    // 4. q1 = f_u @ qw0^T + qb0
    mfma_linear_kernel<0><<<dim3(4, 147, 1), 256, 0, stream>>>(A, 0, qw, 0, qb, 0,
                                                               q1b, 0, 9408, 512, 256, 0);
    // 5-6. k1/v1 from x
    mfma_linear_kernel<0><<<dim3(4, 13, 1), 256, 0, stream>>>(x, 0, kw, 0, kb, 0,
                                                              k1b, 0, 784, 512, 256, 0);
    mfma_linear_kernel<0><<<dim3(8, 13, 1), 256, 0, stream>>>(x, 0, vw, 0, vb, 0,
                                                              v1b, 0, 784, 512, 512, 0);
    // 7. feat = attn1
    attn1_kernel<<<dim3(16, 12), 256, 0, stream>>>(q1b, k1b, v1b, Bb);
    // 8-10. q2/k2 (bf16 out), v2 (fp32) from feat
    mfma_linear_kernel<1><<<dim3(4, 147, 1), 256, 0, stream>>>(Bb, 0, qw + 131072, 0, qb + 256, 0,
                                                               q2bf, 0, 9408, 512, 256, 0);
    mfma_linear_kernel<1><<<dim3(4, 147, 1), 256, 0, stream>>>(Bb, 0, kw + 131072, 0, kb + 256, 0,
                                                               k2bf, 0, 9408, 512, 256, 0);
    mfma_linear_kernel<0><<<dim3(8, 147, 1), 256, 0, stream>>>(Bb, 0, vw + 262144, 0, vb + 512, 0,
                                                               v2b, 0, 9408, 512, 512, 0);
    // 11. w2vT = (v2 @ ep_w^T) transposed per-tile, bf16. Pre-zero so pad keys are 0.
    hipMemsetAsync(w2vT, 0, (size_t)12 * 16 * 512 * 64 * sizeof(short), stream);
    mfma_linear_kernel<2><<<dim3(8, 147, 1), 256, 0, stream>>>(v2b, 0, ep_w, 0, nullptr, 0,
                                                               w2vT, 0, 9408, 512, 512, 0);
    // 12-14. MFMA attn2 + edge BN
    hipMemsetAsync(stats, 0, 288 * sizeof(float), stream);
    attn2_mfma_kernel<<<dim3(16, 12, 12), 256, 0, stream>>>(q2bf, k2bf, w2vT, ep_b, fe, stats);
    edge_fin_kernel<<<144, 256, 0, stream>>>(stats, fe);

    // 15-16. two GCN blocks
    for (int blk = 0; blk < 2; blk++) {
        const float* gw = gnn_w + blk * 5 * 262144;  // U,V,A,B,E
        mfma_linear_kernel<0><<<dim3(8, 3, 4), 256, 0, stream>>>(fv, 0, gw, 262144, nullptr, 0,
                                                                 nodeproj, 98304, 192, 512, 512, 0);
        mfma_linear_kernel<0><<<dim3(8, 36, 1), 256, 0, stream>>>(fe, 0, gw + 4 * 262144, 0, nullptr, 0,
                                                                  eE, 0, 2304, 512, 512, 0);
        gnn_edge_kernel<<<144, 256, 0, stream>>>(nodeproj, eE, fe);
        hipMemsetAsync(xn, 0, 98304 * sizeof(float), stream);
        gnn_agg_kernel<<<dim3(16, 12), 256, 0, stream>>>(fe, nodeproj, xn);
        gnn_node_kernel<<<12, 256, 0, stream>>>(xn, nodeproj, fv);
    }

    // 17. pairwise gather
    pair_gather_kernel<<<dim3(66, 16), 256, 0, stream>>>(fe, fv, pairX);
    // 18-19. MLP layers 1-2
    mfma_linear_kernel<0><<<dim3(8, 17, 2), 256, 0, stream>>>(pairX, 1081344, mlp_w1, 524288, mlp_b1, 512,
                                                              mid1, 540672, 1056, 1024, 512, 1);
    mfma_linear_kernel<0><<<dim3(4, 17, 2), 256, 0, stream>>>(mid1, 540672, mlp_w2, 131072, mlp_b2, 256,
                                                              mid2, 270336, 1056, 512, 256, 1);
    // 20. MLP layer 3
    mlp3_kernel<<<33, 256, 0, stream>>>(mid2, mlp_w3, mlp_b3, mid3);
    // 21. final head
    final_kernel<<<17, 256, 0, stream>>>(mid3, fin_w, fin_b, out);
}

// Round 9
// 496.689 us; speedup vs baseline: 6.2921x; 1.0241x over previous
//
#include <hip/hip_runtime.h>

#define BN_EPS 1e-5f

typedef float f32x4 __attribute__((ext_vector_type(4)));
typedef short s16x8 __attribute__((ext_vector_type(8)));

__device__ __forceinline__ short f2bf(float f) {
    unsigned u = __builtin_bit_cast(unsigned, f);
    u = (u + 0x7fffu + ((u >> 16) & 1u)) >> 16;   // RNE
    return (short)u;
}

// ============ MFMA bf16 linear: Y = act(X @ W^T + b), fp32 in ============
// OMODE 0: fp32 out row-major. 1: bf16 out row-major. 2: bf16 out, transposed
// per-49-row tile -> [tile][Cout=512][64] (keys padded to 64; pad pre-zeroed by host memset).
template<int OMODE>
__global__ __launch_bounds__(256) void mfma_linear_kernel(
    const float* __restrict__ X, int Xstride,
    const float* __restrict__ W, int Wstride,
    const float* __restrict__ bias, int bstride,
    void* __restrict__ Yv, int Ystride,
    int R, int Cin, int Cout, int relu)
{
    const int mat = blockIdx.z;
    X += (size_t)mat * Xstride;
    W += (size_t)mat * Wstride;
    const float* bp = bias ? bias + mat * bstride : nullptr;
    float* Yf = (float*)Yv + (size_t)mat * Ystride;
    short* Ys = (short*)Yv + (size_t)mat * Ystride;

    const int r0 = blockIdx.y * 64;
    const int o0 = blockIdx.x * 64;

    __shared__ short As[64 * 40];   // 80B row stride: 20 banks, 2-way alias = free
    __shared__ short Bs[64 * 40];

    const int tid = threadIdx.x;
    const int lane = tid & 63;
    const int wave = tid >> 6;
    const int wr = wave >> 1, wc = wave & 1;
    const int l15 = lane & 15;
    const int lk = lane >> 4;

    const int trow = tid >> 2;
    const int tseg = (tid & 3) * 8;

    f32x4 acc[2][2] = {};

    const int arow = r0 + trow;
    const bool aok = arow < R;
    const float* xrow = X + (size_t)arow * Cin + tseg;
    const float* wrow = W + (size_t)(o0 + trow) * Cin + tseg;

    for (int k0 = 0; k0 < Cin; k0 += 32) {
        float4 a0 = {}, a1 = {};
        if (aok) {
            a0 = *reinterpret_cast<const float4*>(xrow + k0);
            a1 = *reinterpret_cast<const float4*>(xrow + k0 + 4);
        }
        float4 b0 = *reinterpret_cast<const float4*>(wrow + k0);
        float4 b1 = *reinterpret_cast<const float4*>(wrow + k0 + 4);
        s16x8 av, bv;
        av[0] = f2bf(a0.x); av[1] = f2bf(a0.y); av[2] = f2bf(a0.z); av[3] = f2bf(a0.w);
        av[4] = f2bf(a1.x); av[5] = f2bf(a1.y); av[6] = f2bf(a1.z); av[7] = f2bf(a1.w);
        bv[0] = f2bf(b0.x); bv[1] = f2bf(b0.y); bv[2] = f2bf(b0.z); bv[3] = f2bf(b0.w);
        bv[4] = f2bf(b1.x); bv[5] = f2bf(b1.y); bv[6] = f2bf(b1.z); bv[7] = f2bf(b1.w);
        *reinterpret_cast<s16x8*>(&As[trow * 40 + tseg]) = av;
        *reinterpret_cast<s16x8*>(&Bs[trow * 40 + tseg]) = bv;
        __syncthreads();

        s16x8 af[2], bf[2];
        #pragma unroll
        for (int mi = 0; mi < 2; mi++)
            af[mi] = *reinterpret_cast<const s16x8*>(&As[(wr * 32 + mi * 16 + l15) * 40 + lk * 8]);
        #pragma unroll
        for (int ni = 0; ni < 2; ni++)
            bf[ni] = *reinterpret_cast<const s16x8*>(&Bs[(wc * 32 + ni * 16 + l15) * 40 + lk * 8]);
        #pragma unroll
        for (int mi = 0; mi < 2; mi++)
            #pragma unroll
            for (int ni = 0; ni < 2; ni++)
                acc[mi][ni] = __builtin_amdgcn_mfma_f32_16x16x32_bf16(af[mi], bf[ni], acc[mi][ni], 0, 0, 0);
        __syncthreads();
    }

    #pragma unroll
    for (int mi = 0; mi < 2; mi++) {
        #pragma unroll
        for (int ni = 0; ni < 2; ni++) {
            int col = o0 + wc * 32 + ni * 16 + l15;
            int row0 = r0 + wr * 32 + mi * 16 + lk * 4;
            float bb = bp ? bp[col] : 0.f;
            #pragma unroll
            for (int r = 0; r < 4; r++) {
                int row = row0 + r;
                if (row < R) {
                    float v = acc[mi][ni][r] + bb;
                    if (relu) v = fmaxf(v, 0.f);
                    if (OMODE == 0) {
                        Yf[(size_t)row * Cout + col] = v;
                    } else if (OMODE == 1) {
                        Ys[(size_t)row * Cout + col] = f2bf(v);
                    } else {
                        int t = row / 49, n = row - t * 49;
                        Ys[((size_t)t * 512 + col) * 64 + n] = f2bf(v);
                    }
                }
            }
        }
    }
}

// ============ BN1 partial stats: grid (12, 8); atomicAdd (sum, sumsq) per (k,o) ============
__global__ __launch_bounds__(256) void bn1_partial_kernel(
    const float* __restrict__ h, float* __restrict__ bsum, float* __restrict__ bsq)
{
    int k = blockIdx.x;
    int part = blockIdx.y;
    int tid = threadIdx.x;
    #pragma unroll
    for (int half = 0; half < 2; half++) {
        int o = tid + half * 256;
        const float* base = h + (size_t)k * 401408 + (size_t)part * 98 * 512 + o;
        float s = 0.f, sq = 0.f;
        #pragma unroll 7
        for (int bn = 0; bn < 98; bn++) {
            float v = base[bn * 512];
            s += v; sq += v * v;
        }
        atomicAdd(&bsum[k * 512 + o], s);
        atomicAdd(&bsq[k * 512 + o], sq);
    }
}

// ============ f_u = relu(bn(h)) in place; f_v = mean_n f_u ============
__global__ __launch_bounds__(256) void fu_fv_kernel(
    float* __restrict__ h, const float* __restrict__ bsum,
    const float* __restrict__ bsq, float* __restrict__ f_v)
{
    int b = blockIdx.x;
    int k = blockIdx.y;
    int tid = threadIdx.x;
    #pragma unroll
    for (int half = 0; half < 2; half++) {
        int o = tid + half * 256;
        float mu = bsum[k * 512 + o] * (1.f / 784.f);
        float var = bsq[k * 512 + o] * (1.f / 784.f) - mu * mu;
        float rs = rsqrtf(var + BN_EPS);
        float* base = h + (size_t)(k * 16 + b) * 49 * 512 + o;
        float acc = 0.f;
        #pragma unroll 7
        for (int n = 0; n < 49; n++) {
            float v = (base[n * 512] - mu) * rs;
            v = fmaxf(v, 0.f);
            base[n * 512] = v;
            acc += v;
        }
        f_v[(b * 12 + k) * 512 + o] = acc * (1.f / 49.f);
    }
}

// ============ attn1 (fp32 VALU; tile L2-resident) ============
__global__ __launch_bounds__(256) void attn1_kernel(
    const float* __restrict__ q1,  // (12,16,49,256)
    const float* __restrict__ k1,  // (16,49,256)
    const float* __restrict__ v1,  // (16,49,512)
    float* __restrict__ feat)      // (12,16,49,512)
{
    int b = blockIdx.x;
    int k = blockIdx.y;
    __shared__ float ks[49 * 260];
    __shared__ float Pt[49 * 56];
    int tid = threadIdx.x;
    const float* kb = k1 + b * 49 * 256;
    for (int e = tid; e < 49 * 256; e += 256) ks[(e >> 8) * 260 + (e & 255)] = kb[e];
    __syncthreads();
    const float* qb = q1 + (k * 16 + b) * 49 * 256;
    for (int e = tid; e < 49 * 49; e += 256) {
        int qi = e / 49, kj = e - qi * 49;
        const float4* q4 = reinterpret_cast<const float4*>(qb + qi * 256);
        const float4* k4 = reinterpret_cast<const float4*>(ks + kj * 260);
        float s = 0.f;
        #pragma unroll 8
        for (int d = 0; d < 64; d++) {
            float4 a = q4[d], c = k4[d];
            s += a.x * c.x + a.y * c.y + a.z * c.z + a.w * c.w;
        }
        Pt[kj * 56 + qi] = s * 0.0625f;
    }
    __syncthreads();
    if (tid < 196) {
        int qi = tid >> 2, sub = tid & 3;
        float ev[13];
        float m = -1e30f;
        #pragma unroll 13
        for (int t = 0; t < 13; t++) {
            int j = sub + t * 4;
            ev[t] = (j < 49) ? Pt[j * 56 + qi] : -1e30f;
            m = fmaxf(m, ev[t]);
        }
        m = fmaxf(m, __shfl_xor(m, 1));
        m = fmaxf(m, __shfl_xor(m, 2));
        float s = 0.f;
        #pragma unroll 13
        for (int t = 0; t < 13; t++) { ev[t] = __expf(ev[t] - m); s += ev[t]; }
        s += __shfl_xor(s, 1);
        s += __shfl_xor(s, 2);
        float inv = 1.f / s;
        #pragma unroll 13
        for (int t = 0; t < 13; t++) {
            int j = sub + t * 4;
            if (j < 49) Pt[j * 56 + qi] = ev[t] * inv;
        }
    }
    __syncthreads();
    const float* vb = v1 + b * 49 * 512;
    float* fb = feat + (k * 16 + b) * 49 * 512;
    for (int qc = 0; qc < 49; qc += 8) {
        int nq = 49 - qc; if (nq > 8) nq = 8;
        float a0[8] = {}, a1[8] = {};
        for (int kj = 0; kj < 49; kj++) {
            float v0 = vb[kj * 512 + tid];
            float v1v = vb[kj * 512 + 256 + tid];
            const float4* pr = reinterpret_cast<const float4*>(&Pt[kj * 56 + qc]);
            float4 p0 = pr[0], p1 = pr[1];
            a0[0] += p0.x * v0; a1[0] += p0.x * v1v;
            a0[1] += p0.y * v0; a1[1] += p0.y * v1v;
            a0[2] += p0.z * v0; a1[2] += p0.z * v1v;
            a0[3] += p0.w * v0; a1[3] += p0.w * v1v;
            a0[4] += p1.x * v0; a1[4] += p1.x * v1v;
            a0[5] += p1.y * v0; a1[5] += p1.y * v1v;
            a0[6] += p1.z * v0; a1[6] += p1.z * v1v;
            a0[7] += p1.w * v0; a1[7] += p1.w * v1v;
        }
        #pragma unroll 8
        for (int u = 0; u < 8; u++) {
            if (u < nq) {
                fb[(qc + u) * 512 + tid] = a0[u];
                fb[(qc + u) * 512 + 256 + tid] = a1[u];
            }
        }
    }
}

// ============ attn2 MFMA v2: one block per (b,i), loops all 12 j; V staged in LDS ============
// q2/k2: bf16 (12,16,49,256). w2vT: bf16 (12,16) tiles of [512][64].
// Vs swizzle: 16B chunk index within a 128B row XORed with (row&7) -> 2-way banks on read.
__global__ __launch_bounds__(256) void attn2_mfma_kernel(
    const short* __restrict__ q2,
    const short* __restrict__ k2,
    const short* __restrict__ w2vT,
    const float* __restrict__ ep_b,
    float* __restrict__ fe_raw,     // (16,144,512)
    float* __restrict__ stats)      // (144,2)
{
    const int b = blockIdx.x, i = blockIdx.y;
    __shared__ short Vs[512 * 64];  // 64 KB, swizzled
    __shared__ float S[64 * 68];    // fp32 scores [q][key]
    __shared__ short P[64 * 88];    // bf16 probs  [q][key]
    const int tid = threadIdx.x;
    const int lane = tid & 63, w = tid >> 6;
    const int l15 = lane & 15, lk = lane >> 4;

    // ---- stage V tile into LDS (swizzled), zero P once ----
    {
        const float4* src = reinterpret_cast<const float4*>(w2vT + (size_t)((i * 16 + b) * 512) * 64);
        float4* dst = reinterpret_cast<float4*>(Vs);
        #pragma unroll
        for (int it = 0; it < 16; it++) {
            int c = tid + it * 256;              // 16B chunk 0..4095
            int ch = c >> 3, c8 = c & 7;         // row, chunk-in-row
            dst[(ch << 3) | (c8 ^ (ch & 7))] = src[c];
        }
        for (int idx = tid; idx < 64 * 88; idx += 256) P[idx] = 0;
    }
    const short* kb = k2 + (size_t)((i * 16 + b) * 49) * 256;
    __syncthreads();

    for (int j = 0; j < 12; j++) {
        const short* qb = q2 + (size_t)((j * 16 + b) * 49) * 256;
        // ---- QK^T: wave w computes S rows w*16..+15, all 64 key-cols ----
        {
            int qrow = w * 16 + l15; if (qrow > 48) qrow = 48;
            f32x4 sacc[4] = {};
            #pragma unroll
            for (int ks = 0; ks < 8; ks++) {
                s16x8 aq = *reinterpret_cast<const s16x8*>(qb + (size_t)qrow * 256 + ks * 32 + lk * 8);
                #pragma unroll
                for (int ni = 0; ni < 4; ni++) {
                    int krow = ni * 16 + l15; if (krow > 48) krow = 48;
                    s16x8 bk = *reinterpret_cast<const s16x8*>(kb + (size_t)krow * 256 + ks * 32 + lk * 8);
                    sacc[ni] = __builtin_amdgcn_mfma_f32_16x16x32_bf16(aq, bk, sacc[ni], 0, 0, 0);
                }
            }
            #pragma unroll
            for (int ni = 0; ni < 4; ni++)
                #pragma unroll
                for (int r = 0; r < 4; r++)
                    S[(w * 16 + lk * 4 + r) * 68 + ni * 16 + l15] = sacc[ni][r] * 0.0625f;
        }
        __syncthreads();

        // ---- softmax rows 0..48 over keys 0..48 ----
        if (tid < 196) {
            int qi = tid >> 2, sub = tid & 3;
            float ev[13];
            float m = -1e30f;
            #pragma unroll 13
            for (int t = 0; t < 13; t++) {
                int kk = sub + t * 4;
                ev[t] = (kk < 49) ? S[qi * 68 + kk] : -1e30f;
                m = fmaxf(m, ev[t]);
            }
            m = fmaxf(m, __shfl_xor(m, 1));
            m = fmaxf(m, __shfl_xor(m, 2));
            float s = 0.f;
            #pragma unroll 13
            for (int t = 0; t < 13; t++) { ev[t] = __expf(ev[t] - m); s += ev[t]; }
            s += __shfl_xor(s, 1);
            s += __shfl_xor(s, 2);
            float inv = 1.f / s;
            #pragma unroll 13
            for (int t = 0; t < 13; t++) {
                int kk = sub + t * 4;
                if (kk < 49) P[qi * 88 + kk] = f2bf(ev[t] * inv);
            }
        }
        __syncthreads();

        // ---- PV from LDS V; wave w owns 64 channels per half ----
        const int slot = i * 12 + j;
        float tot = 0.f, csq = 0.f;
        #pragma unroll
        for (int half = 0; half < 2; half++) {
            const int cb = half * 256 + w * 64;
            f32x4 pac[4][4] = {};
            #pragma unroll
            for (int ks = 0; ks < 2; ks++) {
                s16x8 bv[4];
                #pragma unroll
                for (int ni = 0; ni < 4; ni++) {
                    int ch = cb + ni * 16 + l15;
                    int boff = ((ch * 64 + ks * 32 + lk * 8) * 2) ^ ((ch & 7) << 4);
                    bv[ni] = *reinterpret_cast<const s16x8*>(reinterpret_cast<const char*>(Vs) + boff);
                }
                #pragma unroll
                for (int mi = 0; mi < 4; mi++) {
                    s16x8 ap = *reinterpret_cast<const s16x8*>(&P[(mi * 16 + l15) * 88 + ks * 32 + lk * 8]);
                    #pragma unroll
                    for (int ni = 0; ni < 4; ni++)
                        pac[mi][ni] = __builtin_amdgcn_mfma_f32_16x16x32_bf16(ap, bv[ni], pac[mi][ni], 0, 0, 0);
                }
            }
            #pragma unroll
            for (int ni = 0; ni < 4; ni++) {
                int col = cb + ni * 16 + l15;
                float bias = ep_b[col];
                float cs = 0.f;
                #pragma unroll
                for (int mi = 0; mi < 4; mi++) {
                    #pragma unroll
                    for (int r = 0; r < 4; r++) {
                        int row = mi * 16 + lk * 4 + r;
                        if (row < 49) {
                            float sv = pac[mi][ni][r] + bias;
                            cs += sv; csq += sv * sv;
                        }
                    }
                }
                tot += cs;
                cs += __shfl_xor(cs, 16);
                cs += __shfl_xor(cs, 32);
                if (lk == 0)
                    fe_raw[((size_t)b * 144 + slot) * 512 + col] = cs * (1.f / 49.f);
            }
        }
        // wave-level stats reduce + one atomic per wave
        tot += __shfl_xor(tot, 1);  tot += __shfl_xor(tot, 2);  tot += __shfl_xor(tot, 4);
        tot += __shfl_xor(tot, 8);  tot += __shfl_xor(tot, 16); tot += __shfl_xor(tot, 32);
        csq += __shfl_xor(csq, 1);  csq += __shfl_xor(csq, 2);  csq += __shfl_xor(csq, 4);
        csq += __shfl_xor(csq, 8);  csq += __shfl_xor(csq, 16); csq += __shfl_xor(csq, 32);
        if (lane == 0) {
            atomicAdd(&stats[slot * 2], tot);
            atomicAdd(&stats[slot * 2 + 1], csq);
        }
        // next j: S-writes happen after this barrier region's softmax reads (see phase analysis);
        // P-writes of next j are gated by its own post-QK barrier. No extra barrier needed.
    }
}

// ============ finalize edge BN ============
__global__ __launch_bounds__(256) void edge_fin_kernel(
    const float* __restrict__ stats, float* __restrict__ fe)
{
    int s = blockIdx.x;
    const float inv = 1.f / 401408.f;
    float mu = stats[s * 2] * inv;
    float var = stats[s * 2 + 1] * inv - mu * mu;
    float rs = rsqrtf(var + BN_EPS);
    int tid = threadIdx.x;
    for (int b = 0; b < 16; b++) {
        float* p = fe + (b * 144 + s) * 512;
        #pragma unroll
        for (int half = 0; half < 2; half++) {
            int c = tid + half * 256;
            p[c] = (p[c] - mu) * rs;
        }
    }
}

// ============ GNN edge update ============
__global__ __launch_bounds__(256) void gnn_edge_kernel(
    const float* __restrict__ nodeproj,
    const float* __restrict__ eE,
    float* __restrict__ fe)
{
    int s = blockIdx.x;
    int i = s / 12, j = s - i * 12;
    int tid = threadIdx.x;
    const float* Vix = nodeproj + 2 * 98304;
    const float* Vjx = nodeproj + 3 * 98304;
    __shared__ float red[256];
    float msg[32];
    float sum = 0.f, sq = 0.f;
    int idx = 0;
    for (int b = 0; b < 16; b++) {
        #pragma unroll
        for (int half = 0; half < 2; half++) {
            int c = tid + half * 256;
            float v = Vjx[(b * 12 + i) * 512 + c] + Vix[(b * 12 + j) * 512 + c]
                    + eE[(b * 144 + s) * 512 + c];
            msg[idx++] = v;
            sum += v; sq += v * v;
        }
    }
    red[tid] = sum; __syncthreads();
    for (int t = 128; t > 0; t >>= 1) { if (tid < t) red[tid] += red[tid + t]; __syncthreads(); }
    float tsum = red[0]; __syncthreads();
    red[tid] = sq; __syncthreads();
    for (int t = 128; t > 0; t >>= 1) { if (tid < t) red[tid] += red[tid + t]; __syncthreads(); }
    float tsq = red[0];
    float mu = tsum * (1.f / 8192.f);
    float var = tsq * (1.f / 8192.f) - mu * mu;
    float rs = rsqrtf(var + BN_EPS);
    idx = 0;
    for (int b = 0; b < 16; b++) {
        #pragma unroll
        for (int half = 0; half < 2; half++) {
            int c = tid + half * 256;
            float v = fmaxf((msg[idx++] - mu) * rs, 0.f);
            fe[(b * 144 + s) * 512 + c] += v;
        }
    }
}

// ============ GNN aggregation: grid (16,12) over (b, source i); atomicAdd into xn_agg ============
__global__ __launch_bounds__(256) void gnn_agg_kernel(
    const float* __restrict__ fe,
    const float* __restrict__ nodeproj,  // 1=Ujx at +98304
    float* __restrict__ xn_agg)          // (16,12,512), pre-zeroed
{
    int b = blockIdx.x;
    int i = blockIdx.y;
    int tid = threadIdx.x;
    const float* Ujx = nodeproj + 98304;
    #pragma unroll
    for (int half = 0; half < 2; half++) {
        int c = tid + half * 256;
        float sg[12];
        float m = -1e30f;
        #pragma unroll
        for (int j = 0; j < 12; j++) {
            float e = fe[(b * 144 + i * 12 + j) * 512 + c];
            float sv = 1.f / (1.f + __expf(-e));
            sg[j] = sv;
            m = fmaxf(m, sv);
        }
        float ssum = 0.f;
        #pragma unroll
        for (int j = 0; j < 12; j++) { float evv = __expf(sg[j] - m); sg[j] = evv; ssum += evv; }
        float wgt = Ujx[(b * 12 + i) * 512 + c] / ssum;
        #pragma unroll
        for (int j = 0; j < 12; j++)
            atomicAdd(&xn_agg[(b * 12 + j) * 512 + c], sg[j] * wgt);
    }
}

// ============ GNN node update: val = Ux + xn_agg/12 ; fv = relu(fv + bn_class(val)) ============
__global__ __launch_bounds__(256) void gnn_node_kernel(
    const float* __restrict__ xn_agg, const float* __restrict__ nodeproj,
    float* __restrict__ fv)
{
    int k = blockIdx.x;
    int tid = threadIdx.x;
    const float* Ux = nodeproj;
    __shared__ float red[256];
    float vals[32];
    float sum = 0.f, sq = 0.f;
    int idx = 0;
    for (int b = 0; b < 16; b++) {
        #pragma unroll
        for (int half = 0; half < 2; half++) {
            int c = tid + half * 256;
            int o = (b * 12 + k) * 512 + c;
            float v = Ux[o] + xn_agg[o] * (1.f / 12.f);
            vals[idx++] = v;
            sum += v; sq += v * v;
        }
    }
    red[tid] = sum; __syncthreads();
    for (int t = 128; t > 0; t >>= 1) { if (tid < t) red[tid] += red[tid + t]; __syncthreads(); }
    float tsum = red[0]; __syncthreads();
    red[tid] = sq; __syncthreads();
    for (int t = 128; t > 0; t >>= 1) { if (tid < t) red[tid] += red[tid + t]; __syncthreads(); }
    float tsq = red[0];
    float mu = tsum * (1.f / 8192.f);
    float var = tsq * (1.f / 8192.f) - mu * mu;
    float rs = rsqrtf(var + BN_EPS);
    idx = 0;
    for (int b = 0; b < 16; b++) {
        #pragma unroll
        for (int half = 0; half < 2; half++) {
            int c = tid + half * 256;
            int o = (b * 12 + k) * 512 + c;
            float v = (vals[idx++] - mu) * rs;
            fv[o] = fmaxf(fv[o] + v, 0.f);
        }
    }
}

// ============ pairwise gather ============
__global__ __launch_bounds__(256) void pair_gather_kernel(
    const float* __restrict__ fe, const float* __restrict__ fv, float* __restrict__ pairX)
{
    int p = blockIdx.x;
    int b = blockIdx.y;
    int tid = threadIdx.x;
    int i = 0, rem = p;
    while (rem >= 11 - i) { rem -= 11 - i; i++; }
    int j = i + 1 + rem;
    float* e_out = pairX + (b * 66 + p) * 1024;
    float* n_out = pairX + 1056 * 1024 + (b * 66 + p) * 1024;
    const float* fe_ij = fe + (b * 144 + i * 12 + j) * 512;
    const float* fe_ji = fe + (b * 144 + j * 12 + i) * 512;
    const float* fv_i = fv + (b * 12 + i) * 512;
    const float* fv_j = fv + (b * 12 + j) * 512;
    #pragma unroll
    for (int half = 0; half < 2; half++) {
        int c = tid + half * 256;
        e_out[c] = fe_ij[c];
        e_out[512 + c] = fe_ji[c];
        n_out[c] = fv_i[c];
        n_out[512 + c] = fv_j[c];
    }
}

// ============ MLP layer 3 (Cout=4) ============
__global__ __launch_bounds__(256) void mlp3_kernel(
    const float* __restrict__ X,
    const float* __restrict__ w3,
    const float* __restrict__ b3,
    float* __restrict__ Y)
{
    int idx = blockIdx.x * 256 + threadIdx.x;
    if (idx >= 8448) return;
    int o = idx & 3;
    int r = (idx >> 2) % 1056;
    int m = idx / (4 * 1056);
    const float* x = X + (m * 1056 + r) * 256;
    const float* w = w3 + (m * 4 + o) * 256;
    float s = b3[m * 4 + o];
    #pragma unroll 8
    for (int c = 0; c < 256; c++) s += x[c] * w[c];
    Y[idx] = s;
}

// ============ final head ============
__global__ __launch_bounds__(256) void final_kernel(
    const float* __restrict__ mid3,
    const float* __restrict__ fw,
    const float* __restrict__ fb,
    float* __restrict__ out)
{
    int idx = blockIdx.x * 256 + threadIdx.x;
    if (idx >= 4224) return;
    int o = idx & 3;
    int r = idx >> 2;
    const float* ed = mid3 + r * 4;
    const float* nd = mid3 + 1056 * 4 + r * 4;
    float s = fb[o];
    #pragma unroll
    for (int q = 0; q < 4; q++) s += ed[q] * fw[o * 8 + q];
    #pragma unroll
    for (int q = 0; q < 4; q++) s += nd[q] * fw[o * 8 + 4 + q];
    out[idx] = s;
}

extern "C" void kernel_launch(void* const* d_in, const int* in_sizes, int n_in,
                              void* d_out, int out_size, void* d_ws, size_t ws_size,
                              hipStream_t stream)
{
    const float* x      = (const float*)d_in[0];
    const float* cls_w  = (const float*)d_in[1];
    const float* cls_b  = (const float*)d_in[2];
    const float* qw     = (const float*)d_in[3];
    const float* qb     = (const float*)d_in[4];
    const float* kw     = (const float*)d_in[5];
    const float* kb     = (const float*)d_in[6];
    const float* vw     = (const float*)d_in[7];
    const float* vb     = (const float*)d_in[8];
    const float* ep_w   = (const float*)d_in[9];
    const float* ep_b   = (const float*)d_in[10];
    const float* gnn_w  = (const float*)d_in[11];
    const float* mlp_w1 = (const float*)d_in[12];
    const float* mlp_b1 = (const float*)d_in[13];
    const float* mlp_w2 = (const float*)d_in[14];
    const float* mlp_b2 = (const float*)d_in[15];
    const float* mlp_w3 = (const float*)d_in[16];
    const float* mlp_b3 = (const float*)d_in[17];
    const float* fin_w  = (const float*)d_in[18];
    const float* fin_b  = (const float*)d_in[19];
    float* out = (float*)d_out;
    float* ws = (float*)d_ws;

    // ---- workspace layout (floats), ~75 MiB ----
    float* A     = ws;               // 4816896 : h/f_u ; later q2bf+k2bf (bf16)
    float* q1b   = A + 4816896;      // 2408448
    float* k1b   = q1b + 2408448;    // 200704
    float* v1b   = k1b + 200704;     // 401408
    float* Bb    = v1b + 401408;     // 4816896 : feat ; later w2vT (bf16)
    float* Cb    = Bb + 4816896;     // 4816896 : v2 -> gnn temps -> pair temps
    float* fv    = Cb + 4816896;     // 98304
    float* bn1m  = fv + 98304;       // 6144 : Σ per (k,o)
    float* bn1r  = bn1m + 6144;      // 6144 : Σ² per (k,o)
    float* fe    = bn1r + 6144;      // 1179648
    float* stats = fe + 1179648;     // 288

    short* q2bf = (short*)A;                    // (12,16,49,256) bf16
    short* k2bf = (short*)(A + 1204224);        // (12,16,49,256) bf16
    float* v2b  = Cb;                           // (12,16,49,512) fp32
    short* w2vT = (short*)Bb;                   // (12,16,512,64) bf16

    // GNN temps in Cb (after v2 dead)
    float* nodeproj = Cb;            // [4][16][12][512]
    float* eE       = Cb + 393216;
    float* xn       = Cb + 1572864;  // agg accumulator (16,12,512)
    // pair temps in Cb (GNN temps dead)
    float* pairX = Cb;
    float* mid1  = Cb + 2162688;
    float* mid2  = Cb + 3244032;
    float* mid3  = Cb + 3784704;

    // 1. h = x @ cls_w^T + cls_b  (per class)
    mfma_linear_kernel<0><<<dim3(8, 13, 12), 256, 0, stream>>>(x, 0, cls_w, 262144, cls_b, 512,
                                                               A, 401408, 784, 512, 512, 0);
    // 2-3. BN1 stats: parallel partials (12x8 blocks) + fused mu/rstd in fu_fv
    hipMemsetAsync(bn1m, 0, 2 * 6144 * sizeof(float), stream);
    bn1_partial_kernel<<<dim3(12, 8), 256, 0, stream>>>(A, bn1m, bn1r);
    fu_fv_kernel<<<dim3(16, 12), 256, 0, stream>>>(A, bn1m, bn1r, fv);
    // 4. q1 = f_u @ qw0^T + qb0
    mfma_linear_kernel<0><<<dim3(4, 147, 1), 256, 0, stream>>>(A, 0, qw, 0, qb, 0,
                                                               q1b, 0, 9408, 512, 256, 0);
    // 5-6. k1/v1 from x
    mfma_linear_kernel<0><<<dim3(4, 13, 1), 256, 0, stream>>>(x, 0, kw, 0, kb, 0,
                                                              k1b, 0, 784, 512, 256, 0);
    mfma_linear_kernel<0><<<dim3(8, 13, 1), 256, 0, stream>>>(x, 0, vw, 0, vb, 0,
                                                              v1b, 0, 784, 512, 512, 0);
    // 7. feat = attn1
    attn1_kernel<<<dim3(16, 12), 256, 0, stream>>>(q1b, k1b, v1b, Bb);
    // 8-10. q2/k2 (bf16 out), v2 (fp32) from feat
    mfma_linear_kernel<1><<<dim3(4, 147, 1), 256, 0, stream>>>(Bb, 0, qw + 131072, 0, qb + 256, 0,
                                                               q2bf, 0, 9408, 512, 256, 0);
    mfma_linear_kernel<1><<<dim3(4, 147, 1), 256, 0, stream>>>(Bb, 0, kw + 131072, 0, kb + 256, 0,
                                                               k2bf, 0, 9408, 512, 256, 0);
    mfma_linear_kernel<0><<<dim3(8, 147, 1), 256, 0, stream>>>(Bb, 0, vw + 262144, 0, vb + 512, 0,
                                                               v2b, 0, 9408, 512, 512, 0);
    // 11. w2vT = (v2 @ ep_w^T) transposed per-tile, bf16. Pre-zero so pad keys are 0.
    hipMemsetAsync(w2vT, 0, (size_t)12 * 16 * 512 * 64 * sizeof(short), stream);
    mfma_linear_kernel<2><<<dim3(8, 147, 1), 256, 0, stream>>>(v2b, 0, ep_w, 0, nullptr, 0,
                                                               w2vT, 0, 9408, 512, 512, 0);
    // 12-14. MFMA attn2 (V-in-LDS, 12 j per block) + edge BN
    hipMemsetAsync(stats, 0, 288 * sizeof(float), stream);
    attn2_mfma_kernel<<<dim3(16, 12), 256, 0, stream>>>(q2bf, k2bf, w2vT, ep_b, fe, stats);
    edge_fin_kernel<<<144, 256, 0, stream>>>(stats, fe);

    // 15-16. two GCN blocks
    for (int blk = 0; blk < 2; blk++) {
        const float* gw = gnn_w + blk * 5 * 262144;  // U,V,A,B,E
        mfma_linear_kernel<0><<<dim3(8, 3, 4), 256, 0, stream>>>(fv, 0, gw, 262144, nullptr, 0,
                                                                 nodeproj, 98304, 192, 512, 512, 0);
        mfma_linear_kernel<0><<<dim3(8, 36, 1), 256, 0, stream>>>(fe, 0, gw + 4 * 262144, 0, nullptr, 0,
                                                                  eE, 0, 2304, 512, 512, 0);
        gnn_edge_kernel<<<144, 256, 0, stream>>>(nodeproj, eE, fe);
        hipMemsetAsync(xn, 0, 98304 * sizeof(float), stream);
        gnn_agg_kernel<<<dim3(16, 12), 256, 0, stream>>>(fe, nodeproj, xn);
        gnn_node_kernel<<<12, 256, 0, stream>>>(xn, nodeproj, fv);
    }

    // 17. pairwise gather
    pair_gather_kernel<<<dim3(66, 16), 256, 0, stream>>>(fe, fv, pairX);
    // 18-19. MLP layers 1-2
    mfma_linear_kernel<0><<<dim3(8, 17, 2), 256, 0, stream>>>(pairX, 1081344, mlp_w1, 524288, mlp_b1, 512,
                                                              mid1, 540672, 1056, 1024, 512, 1);
    mfma_linear_kernel<0><<<dim3(4, 17, 2), 256, 0, stream>>>(mid1, 540672, mlp_w2, 131072, mlp_b2, 256,
                                                              mid2, 270336, 1056, 512, 256, 1);
    // 20. MLP layer 3
    mlp3_kernel<<<33, 256, 0, stream>>>(mid2, mlp_w3, mlp_b3, mid3);
    // 21. final head
    final_kernel<<<17, 256, 0, stream>>>(mid3, fin_w, fin_b, out);
}